// Round 2
// baseline (436.018 us; speedup 1.0000x reference)
//
#include <hip/hip_runtime.h>

namespace {
constexpr int V = 50000;
constexpr int E = 640000;
constexpr int HALF = 320000;
constexpr int NREL2 = 474;
constexpr int C = 128;
constexpr int NCHUNK = (V + 255) / 256; // 196
}

typedef _Float16 h4 __attribute__((ext_vector_type(4)));
typedef _Float16 h8 __attribute__((ext_vector_type(8)));

// ---------------- precompute: c[k,i], b[k,i], Min[k,i,o], Mout[k,i,o] -------
__global__ void prep_kernel(const float* __restrict__ nrw, const float* __restrict__ nw,
                            const float* __restrict__ inw, const float* __restrict__ outw,
                            const float* __restrict__ aw,
                            float* __restrict__ cbuf, float* __restrict__ bbuf,
                            float* __restrict__ Min, float* __restrict__ Mout) {
  int tid = blockIdx.x * 256 + threadIdx.x;
  if (tid < 512) {
    int k = tid >> 7, i = tid & 127;
    float acc = 0.f;
    for (int d = 0; d < 32; ++d) acc += nrw[k*4096 + i*32 + d] * aw[d];
    cbuf[tid] = acc;
  } else if (tid < 1024) {
    int u = tid - 512; int k = u >> 7, i = u & 127;
    float acc = 0.f;
    for (int d = 0; d < 32; ++d) acc += nw[k*4096 + i*32 + d] * aw[32 + d];
    bbuf[u] = acc;
  } else if (tid < 1024 + 16384) {
    int u = tid - 1024; int k = u >> 12, rem = u & 4095, i = rem >> 5, o = rem & 31;
    float acc = 0.f;
    for (int d = 0; d < 32; ++d) acc += nrw[k*4096 + i*32 + d] * inw[k*1024 + d*32 + o];
    Min[u] = acc;
  } else if (tid < 1024 + 32768) {
    int u = tid - 1024 - 16384; int k = u >> 12, rem = u & 4095, i = rem >> 5, o = rem & 31;
    float acc = 0.f;
    for (int d = 0; d < 32; ++d) acc += nrw[k*4096 + i*32 + d] * outw[k*1024 + d*32 + o];
    Mout[u] = acc;
  }
}

// ---------------- q[t,k] = node_repr[t] . b_k  (16 lanes per node) ----------
__global__ __launch_bounds__(256) void qnode_kernel(const float* __restrict__ nrp,
                                                    const float* __restrict__ bbuf,
                                                    float* __restrict__ qbuf) {
  const int t = blockIdx.x * 16 + (threadIdx.x >> 4);
  const int l = threadIdx.x & 15;
  if (t >= V) return;
  const float* row = nrp + (size_t)t * C + l * 8;
  float4 a0 = *(const float4*)(row);
  float4 a1 = *(const float4*)(row + 4);
  float p[4];
#pragma unroll
  for (int k = 0; k < 4; ++k) {
    const float* brow = bbuf + k * C + l * 8;
    float4 b0 = *(const float4*)(brow);
    float4 b1 = *(const float4*)(brow + 4);
    p[k] = a0.x * b0.x + a0.y * b0.y + a0.z * b0.z + a0.w * b0.w
         + a1.x * b1.x + a1.y * b1.y + a1.z * b1.z + a1.w * b1.w;
  }
#pragma unroll
  for (int m = 1; m < 16; m <<= 1) {
#pragma unroll
    for (int k = 0; k < 4; ++k) p[k] += __shfl_xor(p[k], m);
  }
  if (l == 0) *(float4*)(qbuf + 4 * (size_t)t) = make_float4(p[0], p[1], p[2], p[3]);
}

// ---------------- CSR build (dir-sorted: in-edges first within each node) ---
__global__ void hist_kernel(const int* __restrict__ dst, int* __restrict__ cnt,
                            int* __restrict__ cin) {
  int e = blockIdx.x * 256 + threadIdx.x;
  if (e < E) {
    int t = dst[e];
    atomicAdd(&cnt[t], 1);
    if (e < HALF) atomicAdd(&cin[t], 1);
  }
}

__global__ void scan_sum_kernel(const int* __restrict__ cnt, int* __restrict__ bsum) {
  __shared__ int sd[256];
  int tid = threadIdx.x;
  int idx = blockIdx.x * 256 + tid;
  int v = (idx < V) ? cnt[idx] : 0;
  sd[tid] = v; __syncthreads();
  for (int s = 128; s > 0; s >>= 1) {
    if (tid < s) sd[tid] += sd[tid + s];
    __syncthreads();
  }
  if (tid == 0) bsum[blockIdx.x] = sd[0];
}

__global__ void scan_top_kernel(int* __restrict__ bsum) {
  __shared__ int sd[256];
  int tid = threadIdx.x;
  int v = (tid < NCHUNK) ? bsum[tid] : 0;
  sd[tid] = v; __syncthreads();
  for (int ofs = 1; ofs < 256; ofs <<= 1) {
    int t = (tid >= ofs) ? sd[tid - ofs] : 0;
    __syncthreads();
    sd[tid] += t;
    __syncthreads();
  }
  if (tid < NCHUNK) bsum[tid] = sd[tid] - v;  // exclusive
}

__global__ void scan_apply_kernel(const int* __restrict__ cnt, const int* __restrict__ bsum,
                                  int* __restrict__ off) {
  __shared__ int sd[256];
  int tid = threadIdx.x;
  int idx = blockIdx.x * 256 + tid;
  int v = (idx < V) ? cnt[idx] : 0;
  sd[tid] = v; __syncthreads();
  for (int ofs = 1; ofs < 256; ofs <<= 1) {
    int t = (tid >= ofs) ? sd[tid - ofs] : 0;
    __syncthreads();
    sd[tid] += t;
    __syncthreads();
  }
  if (idx < V) off[idx] = bsum[blockIdx.x] + sd[tid] - v;  // exclusive
}

// place edges: in-edges (e < HALF) packed at off[t], out-edges after cin[t]
__global__ void place_kernel(const int* __restrict__ dst, const int* __restrict__ src,
                             const int* __restrict__ etype, const float* __restrict__ norm,
                             const int* __restrict__ off, const int* __restrict__ cin,
                             int* __restrict__ cur_in, int* __restrict__ cur_out,
                             int* __restrict__ metas, float* __restrict__ norms_s,
                             int* __restrict__ dsts_s) {
  int e = blockIdx.x * 256 + threadIdx.x;
  if (e < E) {
    int t = dst[e];
    int pos;
    if (e < HALF) {
      pos = off[t] + atomicAdd(&cur_in[t], 1);
    } else {
      pos = off[t] + cin[t] + atomicAdd(&cur_out[t], 1);
    }
    metas[pos] = src[e] | (etype[e] << 16) | ((e >= HALF) ? (1 << 25) : 0);
    norms_s[pos] = norm[e];
    dsts_s[pos] = t;
  }
}

// ---------------- phase A: per-edge attention weights (+ optional fp16 x) ---
// Cooperative: 16 lanes per edge. Node/rel rows are read as contiguous 512B
// segments (16B/lane), xs written as a contiguous 256B segment per edge.
template <bool WRITE_XS>
__global__ __launch_bounds__(256) void attw_kernel(
    const float* __restrict__ nrp, const float* __restrict__ rel,
    const int* __restrict__ metas, const float* __restrict__ norms_s,
    const int* __restrict__ dsts_s, const float* __restrict__ qbuf,
    const float* __restrict__ cbuf, float* __restrict__ wbuf,
    _Float16* __restrict__ xs) {
  const int i = blockIdx.x * 16 + (threadIdx.x >> 4);  // edge
  const int l = threadIdx.x & 15;                      // 8-channel chunk
  if (i >= E) return;
  const int meta = metas[i];
  const int s = meta & 0xFFFF;
  const int r = (meta >> 16) & 0x1FF;
  const float* arow = nrp + (size_t)s * C + l * 8;
  const float* brow = rel + (size_t)r * C + l * 8;
  float4 a0 = *(const float4*)(arow);
  float4 a1 = *(const float4*)(arow + 4);
  float4 b0 = *(const float4*)(brow);
  float4 b1 = *(const float4*)(brow + 4);
  float x0 = a0.x * b0.x, x1 = a0.y * b0.y, x2 = a0.z * b0.z, x3 = a0.w * b0.w;
  float x4 = a1.x * b1.x, x5 = a1.y * b1.y, x6 = a1.z * b1.z, x7 = a1.w * b1.w;
  if (WRITE_XS) {
    h8 o;
    o[0] = (_Float16)x0; o[1] = (_Float16)x1; o[2] = (_Float16)x2; o[3] = (_Float16)x3;
    o[4] = (_Float16)x4; o[5] = (_Float16)x5; o[6] = (_Float16)x6; o[7] = (_Float16)x7;
    *(h8*)(xs + (size_t)i * C + l * 8) = o;
  }
  float p[4];
#pragma unroll
  for (int k = 0; k < 4; ++k) {
    const float* crow = cbuf + k * C + l * 8;
    float4 c0 = *(const float4*)(crow);
    float4 c1 = *(const float4*)(crow + 4);
    p[k] = x0 * c0.x + x1 * c0.y + x2 * c0.z + x3 * c0.w
         + x4 * c1.x + x5 * c1.y + x6 * c1.z + x7 * c1.w;
  }
#pragma unroll
  for (int m = 1; m < 16; m <<= 1) {
#pragma unroll
    for (int k = 0; k < 4; ++k) p[k] += __shfl_xor(p[k], m);
  }
  const float nr = norms_s[i];
  const int d = dsts_s[i];
  float4 q4 = *(const float4*)(qbuf + 4 * (size_t)d);
  float l0 = fmaxf(p[0] + q4.x, 0.f);
  float l1 = fmaxf(p[1] + q4.y, 0.f);
  float l2 = fmaxf(p[2] + q4.z, 0.f);
  float l3 = fmaxf(p[3] + q4.w, 0.f);
  float mx = fmaxf(fmaxf(l0, l1), fmaxf(l2, l3));
  float e0 = __expf(l0 - mx), e1 = __expf(l1 - mx);
  float e2 = __expf(l2 - mx), e3 = __expf(l3 - mx);
  float inv = nr / (e0 + e1 + e2 + e3);
  if (l == 0) {
    *(float4*)(wbuf + 4 * (size_t)i) =
        make_float4(e0 * inv, e1 * inv, e2 * inv, e3 * inv);
  }
}

// ---------------- phase B (streaming): z accum from linear xs + contraction -
// wave = node; group 0 (lanes 0-31) accumulates in-edges, group 1 out-edges
// (CSR is dir-sorted, boundary nin[t]). Contraction: thread=(dir,k,o) with
// float4 z LDS reads (broadcast) and 4-way batched coalesced M loads.
__global__ __launch_bounds__(256) void zacc_stream_kernel(
    const _Float16* __restrict__ xs, const float* __restrict__ wbuf,
    const int* __restrict__ cnt, const int* __restrict__ off,
    const int* __restrict__ nin,
    const float* __restrict__ Min, const float* __restrict__ Mout,
    float* __restrict__ h) {
  __shared__ float zli[4][4][132];
  __shared__ float zlo[4][4][132];
  __shared__ float red[4][4][32];
  const int w = threadIdx.x >> 6;
  const int lane = threadIdx.x & 63;
  const int g = lane >> 5;   // 0: in-edges, 1: out-edges
  const int l32 = lane & 31;
  const int t = blockIdx.x * 4 + w;
  const int ch = l32 * 4;

  float4 z[4];
#pragma unroll
  for (int k = 0; k < 4; ++k) z[k] = make_float4(0.f, 0.f, 0.f, 0.f);

  const int start = off[t];
  const int deg = cnt[t];
  const int ni = nin[t];
  const int sidx = g ? ni : 0;
  const int nmy = g ? (deg - ni) : ni;
  const int nmax = max(ni, deg - ni);

  for (int base = 0; base < nmax; base += 4) {
    h4 xv[4];
    float4 wv[4];
#pragma unroll
    for (int u = 0; u < 4; ++u) {
      int j = base + u;
      int e = start + min(sidx + j, deg - 1);
      xv[u] = ((const h4*)xs)[(size_t)e * 32 + l32];
      float4 t4 = ((const float4*)wbuf)[e];
      bool valid = j < nmy;
      wv[u].x = valid ? t4.x : 0.f;
      wv[u].y = valid ? t4.y : 0.f;
      wv[u].z = valid ? t4.z : 0.f;
      wv[u].w = valid ? t4.w : 0.f;
    }
#pragma unroll
    for (int u = 0; u < 4; ++u) {
      float x0 = (float)xv[u].x, x1 = (float)xv[u].y;
      float x2 = (float)xv[u].z, x3 = (float)xv[u].w;
      z[0].x += wv[u].x * x0; z[0].y += wv[u].x * x1;
      z[0].z += wv[u].x * x2; z[0].w += wv[u].x * x3;
      z[1].x += wv[u].y * x0; z[1].y += wv[u].y * x1;
      z[1].z += wv[u].y * x2; z[1].w += wv[u].y * x3;
      z[2].x += wv[u].z * x0; z[2].y += wv[u].z * x1;
      z[2].z += wv[u].z * x2; z[2].w += wv[u].z * x3;
      z[3].x += wv[u].w * x0; z[3].y += wv[u].w * x1;
      z[3].z += wv[u].w * x2; z[3].w += wv[u].w * x3;
    }
  }

  // each group owns its dir completely: direct LDS store, no cross-group shfl
  float* zdst = (g ? &zlo[w][0][0] : &zli[w][0][0]) + ch;
#pragma unroll
  for (int k = 0; k < 4; ++k) *(float4*)(zdst + k * 132) = z[k];
  __syncthreads();

  // contraction: thread = (dir, k, o); 4-i batches: 4 coalesced M loads +
  // 4 broadcast ds_read_b128 of z + 16 FMAs.
  const int tid = threadIdx.x;
  const int dir = tid >> 7;
  const int kk = (tid >> 5) & 3;
  const int o = tid & 31;
  const float* Mp = (dir ? Mout : Min) + kk * 4096 + o;
  const float* zb = (dir ? &zlo[0][0][0] : &zli[0][0][0]) + kk * 132;
  float acc0 = 0.f, acc1 = 0.f, acc2 = 0.f, acc3 = 0.f;
#pragma unroll 4
  for (int i4 = 0; i4 < 32; ++i4) {
    const int i = i4 * 4;
    float m0 = Mp[(i + 0) * 32];
    float m1 = Mp[(i + 1) * 32];
    float m2 = Mp[(i + 2) * 32];
    float m3 = Mp[(i + 3) * 32];
    float4 za = *(const float4*)(zb + 0 * 528 + i);
    float4 zc = *(const float4*)(zb + 1 * 528 + i);
    float4 zd = *(const float4*)(zb + 2 * 528 + i);
    float4 ze = *(const float4*)(zb + 3 * 528 + i);
    acc0 += za.x * m0 + za.y * m1 + za.z * m2 + za.w * m3;
    acc1 += zc.x * m0 + zc.y * m1 + zc.z * m2 + zc.w * m3;
    acc2 += zd.x * m0 + zd.y * m1 + zd.z * m2 + zd.w * m3;
    acc3 += ze.x * m0 + ze.y * m1 + ze.z * m2 + ze.w * m3;
  }
  if (dir) {
    red[0][kk][o] = acc0;
    red[1][kk][o] = acc1;
    red[2][kk][o] = acc2;
    red[3][kk][o] = acc3;
  }
  __syncthreads();
  if (!dir) {
    const float third = 1.f / 3.f;
    h[(size_t)(blockIdx.x * 4 + 0) * C + kk * 32 + o] = (acc0 + red[0][kk][o]) * third;
    h[(size_t)(blockIdx.x * 4 + 1) * C + kk * 32 + o] = (acc1 + red[1][kk][o]) * third;
    h[(size_t)(blockIdx.x * 4 + 2) * C + kk * 32 + o] = (acc2 + red[2][kk][o]) * third;
    h[(size_t)(blockIdx.x * 4 + 3) * C + kk * 32 + o] = (acc3 + red[3][kk][o]) * third;
  }
}

// ---------------- phase B (fallback): gather + accum + contraction ----------
__global__ __launch_bounds__(256) void main2_kernel(
    const float* __restrict__ nrp, const float* __restrict__ rel,
    const int* __restrict__ cnt, const int* __restrict__ off,
    const int* __restrict__ metas, const float* __restrict__ wbuf,
    const float* __restrict__ Min, const float* __restrict__ Mout,
    float* __restrict__ h) {
  __shared__ float zli[4][4][132];
  __shared__ float zlo[4][4][132];
  const int w = threadIdx.x >> 6;
  const int lane = threadIdx.x & 63;
  const int g = lane >> 5;
  const int t = blockIdx.x * 4 + w;
  const int ch = (lane & 31) * 4;

  float4 zi[4], zo[4];
#pragma unroll
  for (int k = 0; k < 4; ++k) {
    zi[k] = make_float4(0.f, 0.f, 0.f, 0.f);
    zo[k] = make_float4(0.f, 0.f, 0.f, 0.f);
  }

  const int start = off[t];
  const int deg = cnt[t];

  for (int base = 0; base < deg; base += 64) {
    const int cn = min(64, deg - base);
    int m_l = 0;
    if (lane < cn) m_l = metas[start + base + lane];
    const int nj = (cn + 1) >> 1;
    int idx0 = min(g, cn - 1);
    bool v0 = (g < cn);
    int mc = __shfl(m_l, idx0);
    float4 wc = *(const float4*)(wbuf + 4 * (size_t)(start + base + idx0));
    if (!v0) { wc.x = 0.f; wc.y = 0.f; wc.z = 0.f; wc.w = 0.f; }
    float4 ac = *(const float4*)(nrp + (size_t)(mc & 0xFFFF) * C + ch);
    float4 bc = *(const float4*)(rel + (size_t)((mc >> 16) & 0x1FF) * C + ch);
    for (int j = 0; j < nj; ++j) {
      int idx1 = 2 * (j + 1) + g;
      bool v1 = (idx1 < cn);
      idx1 = min(idx1, cn - 1);
      int m1 = __shfl(m_l, idx1);
      float4 w1 = *(const float4*)(wbuf + 4 * (size_t)(start + base + idx1));
      if (!v1) { w1.x = 0.f; w1.y = 0.f; w1.z = 0.f; w1.w = 0.f; }
      float4 a1 = *(const float4*)(nrp + (size_t)(m1 & 0xFFFF) * C + ch);
      float4 b1 = *(const float4*)(rel + (size_t)((m1 >> 16) & 0x1FF) * C + ch);

      float4 x;
      x.x = ac.x * bc.x; x.y = ac.y * bc.y; x.z = ac.z * bc.z; x.w = ac.w * bc.w;
      float sif = (mc & (1 << 25)) ? 0.f : 1.f;  // 0 => out-edge
      float wi0 = wc.x * sif, wo0 = wc.x - wi0;
      float wi1 = wc.y * sif, wo1 = wc.y - wi1;
      float wi2 = wc.z * sif, wo2 = wc.z - wi2;
      float wi3 = wc.w * sif, wo3 = wc.w - wi3;
      zi[0].x += wi0 * x.x; zi[0].y += wi0 * x.y; zi[0].z += wi0 * x.z; zi[0].w += wi0 * x.w;
      zi[1].x += wi1 * x.x; zi[1].y += wi1 * x.y; zi[1].z += wi1 * x.z; zi[1].w += wi1 * x.w;
      zi[2].x += wi2 * x.x; zi[2].y += wi2 * x.y; zi[2].z += wi2 * x.z; zi[2].w += wi2 * x.w;
      zi[3].x += wi3 * x.x; zi[3].y += wi3 * x.y; zi[3].z += wi3 * x.z; zi[3].w += wi3 * x.w;
      zo[0].x += wo0 * x.x; zo[0].y += wo0 * x.y; zo[0].z += wo0 * x.z; zo[0].w += wo0 * x.w;
      zo[1].x += wo1 * x.x; zo[1].y += wo1 * x.y; zo[1].z += wo1 * x.z; zo[1].w += wo1 * x.w;
      zo[2].x += wo2 * x.x; zo[2].y += wo2 * x.y; zo[2].z += wo2 * x.z; zo[2].w += wo2 * x.w;
      zo[3].x += wo3 * x.x; zo[3].y += wo3 * x.y; zo[3].z += wo3 * x.z; zo[3].w += wo3 * x.w;
      mc = m1; wc = w1; ac = a1; bc = b1;
    }
  }

#pragma unroll
  for (int k = 0; k < 4; ++k) {
    zi[k].x += __shfl_xor(zi[k].x, 32);
    zi[k].y += __shfl_xor(zi[k].y, 32);
    zi[k].z += __shfl_xor(zi[k].z, 32);
    zi[k].w += __shfl_xor(zi[k].w, 32);
    zo[k].x += __shfl_xor(zo[k].x, 32);
    zo[k].y += __shfl_xor(zo[k].y, 32);
    zo[k].z += __shfl_xor(zo[k].z, 32);
    zo[k].w += __shfl_xor(zo[k].w, 32);
  }
  if (g == 0) {
#pragma unroll
    for (int k = 0; k < 4; ++k) *(float4*)(&zli[w][k][ch]) = zi[k];
  } else {
#pragma unroll
    for (int k = 0; k < 4; ++k) *(float4*)(&zlo[w][k][ch]) = zo[k];
  }
  __syncthreads();

  const int kk = lane >> 4;
  const int o0 = (lane & 15) * 2;
  const float* Mi = Min + kk * 4096 + o0;
  const float* Mo = Mout + kk * 4096 + o0;
  float acc0 = 0.f, acc1 = 0.f;
  for (int i = 0; i < C; ++i) {
    float a_ = zli[w][kk][i];
    float b_ = zlo[w][kk][i];
    float2 mi = *(const float2*)(Mi + i * 32);
    float2 mo = *(const float2*)(Mo + i * 32);
    acc0 += a_ * mi.x + b_ * mo.x;
    acc1 += a_ * mi.y + b_ * mo.y;
  }
  const float third = 1.f / 3.f;
  h[(size_t)t * C + kk * 32 + o0] = acc0 * third;
  h[(size_t)t * C + kk * 32 + o0 + 1] = acc1 * third;
}

// ---------------- self-loop + bias + BN partial stats -----------------------
__global__ __launch_bounds__(256) void selfloop_kernel(
    float* __restrict__ h, const float* __restrict__ lr,
    const float* __restrict__ lw, const float* __restrict__ bias,
    float* __restrict__ bnsum, float* __restrict__ bnsq) {
  __shared__ float lwl[16384];      // 64 KB: lw[i][j]
  __shared__ float xr[4][8][128];   // 16 KB
  __shared__ float red[256];
  const int tid = threadIdx.x;
  const int w = tid >> 6, lane = tid & 63;
  for (int i = tid; i < 16384; i += 256) lwl[i] = lw[i];
  __syncthreads();

  const int c0 = 2 * lane, c1 = c0 + 1;
  const float lr0 = lr[c0], lr1 = lr[c1];
  const float bv0 = bias[c0], bv1 = bias[c1];
  float s0 = 0.f, s1 = 0.f, sq0 = 0.f, sq1 = 0.f;

  const int wg = blockIdx.x * 4 + w;
  const int nw = gridDim.x * 4;
  for (int rb = wg * 8; rb < V; rb += nw * 8) {
    const int nrows = min(8, V - rb);
    float2 hv[8];
#pragma unroll
    for (int rr = 0; rr < 8; ++rr) {
      if (rr < nrows) {
        hv[rr] = *(const float2*)(h + (size_t)(rb + rr) * C + c0);
      } else {
        hv[rr] = make_float2(0.f, 0.f);
      }
      xr[w][rr][c0] = hv[rr].x * lr0;
      xr[w][rr][c1] = hv[rr].y * lr1;
    }
    float acc[8][2] = {};
    for (int i = 0; i < C; ++i) {
      float2 lwv = *(const float2*)(&lwl[i * C + c0]);
#pragma unroll
      for (int rr = 0; rr < 8; ++rr) {
        float xv = xr[w][rr][i];
        acc[rr][0] += xv * lwv.x;
        acc[rr][1] += xv * lwv.y;
      }
    }
    const float third = 1.f / 3.f;
#pragma unroll
    for (int rr = 0; rr < 8; ++rr) {
      if (rr < nrows) {
        float h0 = hv[rr].x + acc[rr][0] * third + bv0;
        float h1 = hv[rr].y + acc[rr][1] * third + bv1;
        *(float2*)(h + (size_t)(rb + rr) * C + c0) = make_float2(h0, h1);
        s0 += h0; s1 += h1; sq0 += h0 * h0; sq1 += h1 * h1;
      }
    }
  }

  __syncthreads();
  red[tid] = s0; __syncthreads();
  if (tid < 64) {
    float v = red[tid] + red[tid + 64] + red[tid + 128] + red[tid + 192];
    atomicAdd(&bnsum[2 * tid], v);
  }
  __syncthreads();
  red[tid] = s1; __syncthreads();
  if (tid < 64) {
    float v = red[tid] + red[tid + 64] + red[tid + 128] + red[tid + 192];
    atomicAdd(&bnsum[2 * tid + 1], v);
  }
  __syncthreads();
  red[tid] = sq0; __syncthreads();
  if (tid < 64) {
    float v = red[tid] + red[tid + 64] + red[tid + 128] + red[tid + 192];
    atomicAdd(&bnsq[2 * tid], v);
  }
  __syncthreads();
  red[tid] = sq1; __syncthreads();
  if (tid < 64) {
    float v = red[tid] + red[tid + 64] + red[tid + 128] + red[tid + 192];
    atomicAdd(&bnsq[2 * tid + 1], v);
  }
}

// ---------------- BN finalize + tanh (fused) --------------------------------
__global__ void tanh_kernel(float* __restrict__ h,
                            const float* __restrict__ bnsum, const float* __restrict__ bnsq,
                            const float* __restrict__ gamma, const float* __restrict__ beta) {
  int idx = blockIdx.x * 256 + threadIdx.x;
  int base = idx * 4;
  if (base >= V * C) return;
  int j = base & 127;
  const float invV = 1.f / (float)V;
  float4 v = *(float4*)(h + base);
  float o[4] = {v.x, v.y, v.z, v.w};
#pragma unroll
  for (int cidx = 0; cidx < 4; ++cidx) {
    float mean = bnsum[j + cidx] * invV;
    float var = bnsq[j + cidx] * invV - mean * mean;
    float sc = gamma[j + cidx] * rsqrtf(var + 1e-5f);
    float sh = beta[j + cidx] - sc * mean;
    o[cidx] = tanhf(sc * o[cidx] + sh);
  }
  v.x = o[0]; v.y = o[1]; v.z = o[2]; v.w = o[3];
  *(float4*)(h + base) = v;
}

// ---------------- rel_out = rel_repr @ w_rel --------------------------------
__global__ __launch_bounds__(128) void relout_kernel(
    const float* __restrict__ rel, const float* __restrict__ wrel,
    float* __restrict__ out) {
  __shared__ float rr[128];
  int tid = threadIdx.x;
  int row = blockIdx.x;
  rr[tid] = rel[row * C + tid];
  __syncthreads();
  float acc = 0.f;
#pragma unroll 4
  for (int i = 0; i < C; ++i) acc += rr[i] * wrel[i * C + tid];
  out[row * C + tid] = acc;
}

extern "C" void kernel_launch(void* const* d_in, const int* in_sizes, int n_in,
                              void* d_out, int out_size, void* d_ws, size_t ws_size,
                              hipStream_t stream) {
  const float* node_repr  = (const float*)d_in[0];
  const float* rel_repr   = (const float*)d_in[1];
  const int*   src        = (const int*)d_in[2];
  const int*   dst        = (const int*)d_in[3];
  const int*   etype      = (const int*)d_in[4];
  const float* norm       = (const float*)d_in[5];
  const float* node_w     = (const float*)d_in[6];
  const float* node_rel_w = (const float*)d_in[7];
  const float* in_w       = (const float*)d_in[8];
  const float* out_w      = (const float*)d_in[9];
  const float* att_w      = (const float*)d_in[10];
  const float* loop_rel   = (const float*)d_in[11];
  const float* loop_w     = (const float*)d_in[12];
  const float* w_rel      = (const float*)d_in[13];
  const float* bias       = (const float*)d_in[14];
  const float* bn_gamma   = (const float*)d_in[15];
  const float* bn_beta    = (const float*)d_in[16];

  float* out = (float*)d_out;
  float* h = out;                       // [V,128] accumulator, finalized in place
  float* rel_out = out + (size_t)V * C; // [474,128]

  // workspace layout (all float4/h4 users stay 16B-aligned)
  int* cnt = (int*)d_ws;                // V
  int* cur_in = cnt + V;                // V
  int* cin = cur_in + V;                // V (in-edge counts, persists)
  int* cur_out = cin + V;               // V
  float* bnsum = (float*)(cur_out + V); // 128
  float* bnsq = bnsum + 128;            // 128  -- zero region ends (4V+256)
  int* off = (int*)(bnsq + 128);        // V
  int* metas = off + V;                 // E
  float* norms_s = (float*)(metas + E); // E
  int* dsts_s = (int*)(norms_s + E);    // E
  float* wbuf = (float*)(dsts_s + E);   // 4E
  int* bsum = (int*)(wbuf + 4 * (size_t)E); // 256
  float* qbuf = (float*)(bsum + 256);   // 4V
  float* cbuf = qbuf + 4 * V;           // 512
  float* bbuf = cbuf + 512;             // 512
  float* Min = bbuf + 512;              // 16384
  float* Mout = Min + 16384;            // 16384
  _Float16* xs = (_Float16*)(Mout + 16384); // E*128 halves (streaming path only)

  const size_t base_bytes = (size_t)((char*)xs - (char*)d_ws);
  const size_t need_bytes = base_bytes + (size_t)E * C * sizeof(_Float16);
  const bool streaming = (ws_size >= need_bytes);

  hipMemsetAsync(cnt, 0, (size_t)(4 * V + 256) * 4, stream);

  prep_kernel<<<(1024 + 32768 + 255) / 256, 256, 0, stream>>>(
      node_rel_w, node_w, in_w, out_w, att_w, cbuf, bbuf, Min, Mout);
  qnode_kernel<<<(V + 15) / 16, 256, 0, stream>>>(node_repr, bbuf, qbuf);
  hist_kernel<<<E / 256, 256, 0, stream>>>(dst, cnt, cin);
  scan_sum_kernel<<<NCHUNK, 256, 0, stream>>>(cnt, bsum);
  scan_top_kernel<<<1, 256, 0, stream>>>(bsum);
  scan_apply_kernel<<<NCHUNK, 256, 0, stream>>>(cnt, bsum, off);
  place_kernel<<<E / 256, 256, 0, stream>>>(dst, src, etype, norm, off, cin,
                                            cur_in, cur_out, metas, norms_s,
                                            dsts_s);
  if (streaming) {
    attw_kernel<true><<<E / 16, 256, 0, stream>>>(node_repr, rel_repr, metas,
                                                  norms_s, dsts_s, qbuf, cbuf,
                                                  wbuf, xs);
    zacc_stream_kernel<<<V / 4, 256, 0, stream>>>(xs, wbuf, cnt, off, cin,
                                                  Min, Mout, h);
  } else {
    attw_kernel<false><<<E / 16, 256, 0, stream>>>(node_repr, rel_repr, metas,
                                                   norms_s, dsts_s, qbuf, cbuf,
                                                   wbuf, nullptr);
    main2_kernel<<<V / 4, 256, 0, stream>>>(node_repr, rel_repr, cnt, off, metas,
                                            wbuf, Min, Mout, h);
  }
  selfloop_kernel<<<1024, 256, 0, stream>>>(h, loop_rel, loop_w, bias, bnsum, bnsq);
  tanh_kernel<<<(V * C / 4 + 255) / 256, 256, 0, stream>>>(h, bnsum, bnsq, bn_gamma, bn_beta);
  relout_kernel<<<NREL2, 128, 0, stream>>>(rel_repr, w_rel, rel_out);
}

// Round 3
// 384.453 us; speedup vs baseline: 1.1341x; 1.1341x over previous
//
#include <hip/hip_runtime.h>

namespace {
constexpr int V = 50000;
constexpr int E = 640000;
constexpr int HALF = 320000;
constexpr int NREL2 = 474;
constexpr int C = 128;
constexpr int NCHUNK = (V + 255) / 256; // 196
}

typedef _Float16 h4 __attribute__((ext_vector_type(4)));
typedef _Float16 h8 __attribute__((ext_vector_type(8)));
typedef _Float16 f16x8 __attribute__((ext_vector_type(8)));
typedef float f32x4 __attribute__((ext_vector_type(4)));

// ---------------- precompute: c[k,i], b[k,i], Min[k,i,o], Mout[k,i,o] -------
__global__ void prep_kernel(const float* __restrict__ nrw, const float* __restrict__ nw,
                            const float* __restrict__ inw, const float* __restrict__ outw,
                            const float* __restrict__ aw,
                            float* __restrict__ cbuf, float* __restrict__ bbuf,
                            float* __restrict__ Min, float* __restrict__ Mout) {
  int tid = blockIdx.x * 256 + threadIdx.x;
  if (tid < 512) {
    int k = tid >> 7, i = tid & 127;
    float acc = 0.f;
    for (int d = 0; d < 32; ++d) acc += nrw[k*4096 + i*32 + d] * aw[d];
    cbuf[tid] = acc;
  } else if (tid < 1024) {
    int u = tid - 512; int k = u >> 7, i = u & 127;
    float acc = 0.f;
    for (int d = 0; d < 32; ++d) acc += nw[k*4096 + i*32 + d] * aw[32 + d];
    bbuf[u] = acc;
  } else if (tid < 1024 + 16384) {
    int u = tid - 1024; int k = u >> 12, rem = u & 4095, i = rem >> 5, o = rem & 31;
    float acc = 0.f;
    for (int d = 0; d < 32; ++d) acc += nrw[k*4096 + i*32 + d] * inw[k*1024 + d*32 + o];
    Min[u] = acc;
  } else if (tid < 1024 + 32768) {
    int u = tid - 1024 - 16384; int k = u >> 12, rem = u & 4095, i = rem >> 5, o = rem & 31;
    float acc = 0.f;
    for (int d = 0; d < 32; ++d) acc += nrw[k*4096 + i*32 + d] * outw[k*1024 + d*32 + o];
    Mout[u] = acc;
  }
}

// ---- Mh: f16 B-fragment layout Mh[dir][k][otile][o16][i128] ----------------
__global__ void mh_kernel(const float* __restrict__ Min, const float* __restrict__ Mout,
                          _Float16* __restrict__ Mh) {
  int u = blockIdx.x * 256 + threadIdx.x;  // 32768 total
  int i = u & 127;
  int o16 = (u >> 7) & 15;
  int ot = (u >> 11) & 1;
  int kk = (u >> 12) & 3;
  int d = (u >> 14) & 1;
  int o = ot * 16 + o16;
  float v = (d ? Mout : Min)[kk * 4096 + i * 32 + o];
  Mh[u] = (_Float16)v;
}

// ---------------- q[t,k] = node_repr[t] . b_k  (16 lanes per node) ----------
__global__ __launch_bounds__(256) void qnode_kernel(const float* __restrict__ nrp,
                                                    const float* __restrict__ bbuf,
                                                    float* __restrict__ qbuf) {
  const int t = blockIdx.x * 16 + (threadIdx.x >> 4);
  const int l = threadIdx.x & 15;
  if (t >= V) return;
  const float* row = nrp + (size_t)t * C + l * 8;
  float4 a0 = *(const float4*)(row);
  float4 a1 = *(const float4*)(row + 4);
  float p[4];
#pragma unroll
  for (int k = 0; k < 4; ++k) {
    const float* brow = bbuf + k * C + l * 8;
    float4 b0 = *(const float4*)(brow);
    float4 b1 = *(const float4*)(brow + 4);
    p[k] = a0.x * b0.x + a0.y * b0.y + a0.z * b0.z + a0.w * b0.w
         + a1.x * b1.x + a1.y * b1.y + a1.z * b1.z + a1.w * b1.w;
  }
#pragma unroll
  for (int m = 1; m < 16; m <<= 1) {
#pragma unroll
    for (int k = 0; k < 4; ++k) p[k] += __shfl_xor(p[k], m);
  }
  if (l == 0) *(float4*)(qbuf + 4 * (size_t)t) = make_float4(p[0], p[1], p[2], p[3]);
}

// ---------------- CSR build (dir-sorted: in-edges first within each node) ---
__global__ void hist_kernel(const int* __restrict__ dst, int* __restrict__ cnt,
                            int* __restrict__ cin) {
  int e = blockIdx.x * 256 + threadIdx.x;
  if (e < E) {
    int t = dst[e];
    atomicAdd(&cnt[t], 1);
    if (e < HALF) atomicAdd(&cin[t], 1);
  }
}

__global__ void scan_sum_kernel(const int* __restrict__ cnt, int* __restrict__ bsum) {
  __shared__ int sd[256];
  int tid = threadIdx.x;
  int idx = blockIdx.x * 256 + tid;
  int v = (idx < V) ? cnt[idx] : 0;
  sd[tid] = v; __syncthreads();
  for (int s = 128; s > 0; s >>= 1) {
    if (tid < s) sd[tid] += sd[tid + s];
    __syncthreads();
  }
  if (tid == 0) bsum[blockIdx.x] = sd[0];
}

__global__ void scan_top_kernel(int* __restrict__ bsum) {
  __shared__ int sd[256];
  int tid = threadIdx.x;
  int v = (tid < NCHUNK) ? bsum[tid] : 0;
  sd[tid] = v; __syncthreads();
  for (int ofs = 1; ofs < 256; ofs <<= 1) {
    int t = (tid >= ofs) ? sd[tid - ofs] : 0;
    __syncthreads();
    sd[tid] += t;
    __syncthreads();
  }
  if (tid < NCHUNK) bsum[tid] = sd[tid] - v;  // exclusive
}

__global__ void scan_apply_kernel(const int* __restrict__ cnt, const int* __restrict__ bsum,
                                  int* __restrict__ off) {
  __shared__ int sd[256];
  int tid = threadIdx.x;
  int idx = blockIdx.x * 256 + tid;
  int v = (idx < V) ? cnt[idx] : 0;
  sd[tid] = v; __syncthreads();
  for (int ofs = 1; ofs < 256; ofs <<= 1) {
    int t = (tid >= ofs) ? sd[tid - ofs] : 0;
    __syncthreads();
    sd[tid] += t;
    __syncthreads();
  }
  if (idx < V) off[idx] = bsum[blockIdx.x] + sd[tid] - v;  // exclusive
}

// place edges: in-edges (e < HALF) packed at off[t], out-edges after cin[t]
__global__ void place_kernel(const int* __restrict__ dst, const int* __restrict__ src,
                             const int* __restrict__ etype, const float* __restrict__ norm,
                             const int* __restrict__ off, const int* __restrict__ cin,
                             int* __restrict__ cur_in, int* __restrict__ cur_out,
                             int* __restrict__ metas, float* __restrict__ norms_s,
                             int* __restrict__ dsts_s) {
  int e = blockIdx.x * 256 + threadIdx.x;
  if (e < E) {
    int t = dst[e];
    int pos;
    if (e < HALF) {
      pos = off[t] + atomicAdd(&cur_in[t], 1);
    } else {
      pos = off[t] + cin[t] + atomicAdd(&cur_out[t], 1);
    }
    metas[pos] = src[e] | (etype[e] << 16) | ((e >= HALF) ? (1 << 25) : 0);
    norms_s[pos] = norm[e];
    dsts_s[pos] = t;
  }
}

// ---------------- phase A: per-edge attention weights (+ optional fp16 x) ---
template <bool WRITE_XS>
__global__ __launch_bounds__(256) void attw_kernel(
    const float* __restrict__ nrp, const float* __restrict__ rel,
    const int* __restrict__ metas, const float* __restrict__ norms_s,
    const int* __restrict__ dsts_s, const float* __restrict__ qbuf,
    const float* __restrict__ cbuf, float* __restrict__ wbuf,
    _Float16* __restrict__ xs) {
  const int i = blockIdx.x * 16 + (threadIdx.x >> 4);  // edge
  const int l = threadIdx.x & 15;                      // 8-channel chunk
  if (i >= E) return;
  const int meta = metas[i];
  const int s = meta & 0xFFFF;
  const int r = (meta >> 16) & 0x1FF;
  const float* arow = nrp + (size_t)s * C + l * 8;
  const float* brow = rel + (size_t)r * C + l * 8;
  float4 a0 = *(const float4*)(arow);
  float4 a1 = *(const float4*)(arow + 4);
  float4 b0 = *(const float4*)(brow);
  float4 b1 = *(const float4*)(brow + 4);
  float x0 = a0.x * b0.x, x1 = a0.y * b0.y, x2 = a0.z * b0.z, x3 = a0.w * b0.w;
  float x4 = a1.x * b1.x, x5 = a1.y * b1.y, x6 = a1.z * b1.z, x7 = a1.w * b1.w;
  if (WRITE_XS) {
    h8 o;
    o[0] = (_Float16)x0; o[1] = (_Float16)x1; o[2] = (_Float16)x2; o[3] = (_Float16)x3;
    o[4] = (_Float16)x4; o[5] = (_Float16)x5; o[6] = (_Float16)x6; o[7] = (_Float16)x7;
    *(h8*)(xs + (size_t)i * C + l * 8) = o;
  }
  float p[4];
#pragma unroll
  for (int k = 0; k < 4; ++k) {
    const float* crow = cbuf + k * C + l * 8;
    float4 c0 = *(const float4*)(crow);
    float4 c1 = *(const float4*)(crow + 4);
    p[k] = x0 * c0.x + x1 * c0.y + x2 * c0.z + x3 * c0.w
         + x4 * c1.x + x5 * c1.y + x6 * c1.z + x7 * c1.w;
  }
#pragma unroll
  for (int m = 1; m < 16; m <<= 1) {
#pragma unroll
    for (int k = 0; k < 4; ++k) p[k] += __shfl_xor(p[k], m);
  }
  const float nr = norms_s[i];
  const int d = dsts_s[i];
  float4 q4 = *(const float4*)(qbuf + 4 * (size_t)d);
  float l0 = fmaxf(p[0] + q4.x, 0.f);
  float l1 = fmaxf(p[1] + q4.y, 0.f);
  float l2 = fmaxf(p[2] + q4.z, 0.f);
  float l3 = fmaxf(p[3] + q4.w, 0.f);
  float mx = fmaxf(fmaxf(l0, l1), fmaxf(l2, l3));
  float e0 = __expf(l0 - mx), e1 = __expf(l1 - mx);
  float e2 = __expf(l2 - mx), e3 = __expf(l3 - mx);
  float inv = nr / (e0 + e1 + e2 + e3);
  if (l == 0) {
    *(float4*)(wbuf + 4 * (size_t)i) =
        make_float4(e0 * inv, e1 * inv, e2 * inv, e3 * inv);
  }
}

// ---------------- phase B (streaming): z accum (f32->f16 LDS) + MFMA --------
// 512 threads, 32 nodes/block. Phase 1: wave w accumulates nodes w*4..w*4+3
// (group 0 = in-edges, group 1 = out-edges; CSR dir-sorted), writes z as f16
// into XOR-swizzled LDS [node][dir][k][i]. Phase 2: wave = (k, node-half),
// 16x16x32 f16 MFMA: C[16 nodes x 16 o] chained over dir(2) x kchunk(4).
__global__ __launch_bounds__(512, 4) void zacc_mfma_kernel(
    const _Float16* __restrict__ xs, const float* __restrict__ wbuf,
    const int* __restrict__ cnt, const int* __restrict__ off,
    const int* __restrict__ nin, const _Float16* __restrict__ Mh,
    float* __restrict__ h) {
  __shared__ __align__(16) _Float16 z16[32768];  // 32 nodes x 2048B, swizzled
  const int w = threadIdx.x >> 6;
  const int lane = threadIdx.x & 63;
  const int g = lane >> 5;   // 0: in-edges, 1: out-edges
  const int l32 = lane & 31;

  // ---- phase 1: accumulate z for this wave's 4 nodes ----
  for (int nn = 0; nn < 4; ++nn) {
    const int node = w * 4 + nn;               // 0..31
    const int t = blockIdx.x * 32 + node;
    int start = 0, deg = 0, ni = 0;
    if (t < V) { start = off[t]; deg = cnt[t]; ni = nin[t]; }
    const int sidx = g ? ni : 0;
    const int nmy = g ? (deg - ni) : ni;
    const int nmax = max(ni, deg - ni);

    float4 z[4];
#pragma unroll
    for (int k = 0; k < 4; ++k) z[k] = make_float4(0.f, 0.f, 0.f, 0.f);

    for (int base = 0; base < nmax; base += 4) {
      h4 xv[4];
      float4 wv[4];
#pragma unroll
      for (int u = 0; u < 4; ++u) {
        int j = base + u;
        int e = start + min(sidx + j, deg - 1);
        xv[u] = ((const h4*)xs)[(size_t)e * 32 + l32];
        float4 t4 = ((const float4*)wbuf)[e];
        bool valid = j < nmy;
        wv[u].x = valid ? t4.x : 0.f;
        wv[u].y = valid ? t4.y : 0.f;
        wv[u].z = valid ? t4.z : 0.f;
        wv[u].w = valid ? t4.w : 0.f;
      }
#pragma unroll
      for (int u = 0; u < 4; ++u) {
        float x0 = (float)xv[u].x, x1 = (float)xv[u].y;
        float x2 = (float)xv[u].z, x3 = (float)xv[u].w;
        z[0].x += wv[u].x * x0; z[0].y += wv[u].x * x1;
        z[0].z += wv[u].x * x2; z[0].w += wv[u].x * x3;
        z[1].x += wv[u].y * x0; z[1].y += wv[u].y * x1;
        z[1].z += wv[u].y * x2; z[1].w += wv[u].y * x3;
        z[2].x += wv[u].z * x0; z[2].y += wv[u].z * x1;
        z[2].z += wv[u].z * x2; z[2].w += wv[u].z * x3;
        z[3].x += wv[u].w * x0; z[3].y += wv[u].w * x1;
        z[3].z += wv[u].w * x2; z[3].w += wv[u].w * x3;
      }
    }

    // write f16 z to swizzled LDS: byte = node*2048 + dir*1024 + k*256
    //                                   + ((l32*8) ^ ((node&7)<<4))
    const int swz = (node & 7) << 4;
    char* zb = (char*)z16 + node * 2048 + g * 1024 + ((l32 * 8) ^ swz);
#pragma unroll
    for (int k = 0; k < 4; ++k) {
      h4 o;
      o.x = (_Float16)z[k].x; o.y = (_Float16)z[k].y;
      o.z = (_Float16)z[k].z; o.w = (_Float16)z[k].w;
      *(h4*)(zb + k * 256) = o;
    }
  }
  __syncthreads();

  // ---- phase 2: MFMA contraction; wave = (k, node-half) ----
  const int kk = w & 3;
  const int nh = w >> 2;
  const int lo16 = lane & 15;       // A row (node) / B col (o) / C col (o)
  const int kq = lane >> 4;         // k-chunk quarter
  {
    const int anode = nh * 16 + lo16;
    const int aswz = (anode & 7) << 4;
    const char* zb = (const char*)z16 + anode * 2048 + kk * 256;
    f16x8 a[2][4];
#pragma unroll
    for (int d = 0; d < 2; ++d)
#pragma unroll
      for (int kc = 0; kc < 4; ++kc)
        a[d][kc] = *(const f16x8*)(zb + d * 1024 + ((kc * 64 + kq * 16) ^ aswz));

    f32x4 c0 = {0.f, 0.f, 0.f, 0.f};
    f32x4 c1 = {0.f, 0.f, 0.f, 0.f};
#pragma unroll
    for (int d = 0; d < 2; ++d)
#pragma unroll
      for (int kc = 0; kc < 4; ++kc) {
        const _Float16* mb = Mh + (((d * 4 + kk) * 2) * 16 + lo16) * 128 + kc * 32 + kq * 8;
        f16x8 b0 = *(const f16x8*)(mb);
        f16x8 b1 = *(const f16x8*)(mb + 2048);
        c0 = __builtin_amdgcn_mfma_f32_16x16x32_f16(a[d][kc], b0, c0, 0, 0, 0);
        c1 = __builtin_amdgcn_mfma_f32_16x16x32_f16(a[d][kc], b1, c1, 0, 0, 0);
      }

    const float third = 1.f / 3.f;
#pragma unroll
    for (int r = 0; r < 4; ++r) {
      int tt = blockIdx.x * 32 + nh * 16 + kq * 4 + r;
      if (tt < V) {
        size_t hb = (size_t)tt * C + kk * 32 + lo16;
        h[hb] = c0[r] * third;
        h[hb + 16] = c1[r] * third;
      }
    }
  }
}

// ---------------- phase B (fallback): gather + accum + contraction ----------
__global__ __launch_bounds__(256) void main2_kernel(
    const float* __restrict__ nrp, const float* __restrict__ rel,
    const int* __restrict__ cnt, const int* __restrict__ off,
    const int* __restrict__ metas, const float* __restrict__ wbuf,
    const float* __restrict__ Min, const float* __restrict__ Mout,
    float* __restrict__ h) {
  __shared__ float zli[4][4][132];
  __shared__ float zlo[4][4][132];
  const int w = threadIdx.x >> 6;
  const int lane = threadIdx.x & 63;
  const int g = lane >> 5;
  const int t = blockIdx.x * 4 + w;
  const int ch = (lane & 31) * 4;

  float4 zi[4], zo[4];
#pragma unroll
  for (int k = 0; k < 4; ++k) {
    zi[k] = make_float4(0.f, 0.f, 0.f, 0.f);
    zo[k] = make_float4(0.f, 0.f, 0.f, 0.f);
  }

  const int start = off[t];
  const int deg = cnt[t];

  for (int base = 0; base < deg; base += 64) {
    const int cn = min(64, deg - base);
    int m_l = 0;
    if (lane < cn) m_l = metas[start + base + lane];
    const int nj = (cn + 1) >> 1;
    int idx0 = min(g, cn - 1);
    bool v0 = (g < cn);
    int mc = __shfl(m_l, idx0);
    float4 wc = *(const float4*)(wbuf + 4 * (size_t)(start + base + idx0));
    if (!v0) { wc.x = 0.f; wc.y = 0.f; wc.z = 0.f; wc.w = 0.f; }
    float4 ac = *(const float4*)(nrp + (size_t)(mc & 0xFFFF) * C + ch);
    float4 bc = *(const float4*)(rel + (size_t)((mc >> 16) & 0x1FF) * C + ch);
    for (int j = 0; j < nj; ++j) {
      int idx1 = 2 * (j + 1) + g;
      bool v1 = (idx1 < cn);
      idx1 = min(idx1, cn - 1);
      int m1 = __shfl(m_l, idx1);
      float4 w1 = *(const float4*)(wbuf + 4 * (size_t)(start + base + idx1));
      if (!v1) { w1.x = 0.f; w1.y = 0.f; w1.z = 0.f; w1.w = 0.f; }
      float4 a1 = *(const float4*)(nrp + (size_t)(m1 & 0xFFFF) * C + ch);
      float4 b1 = *(const float4*)(rel + (size_t)((m1 >> 16) & 0x1FF) * C + ch);

      float4 x;
      x.x = ac.x * bc.x; x.y = ac.y * bc.y; x.z = ac.z * bc.z; x.w = ac.w * bc.w;
      float sif = (mc & (1 << 25)) ? 0.f : 1.f;  // 0 => out-edge
      float wi0 = wc.x * sif, wo0 = wc.x - wi0;
      float wi1 = wc.y * sif, wo1 = wc.y - wi1;
      float wi2 = wc.z * sif, wo2 = wc.z - wi2;
      float wi3 = wc.w * sif, wo3 = wc.w - wi3;
      zi[0].x += wi0 * x.x; zi[0].y += wi0 * x.y; zi[0].z += wi0 * x.z; zi[0].w += wi0 * x.w;
      zi[1].x += wi1 * x.x; zi[1].y += wi1 * x.y; zi[1].z += wi1 * x.z; zi[1].w += wi1 * x.w;
      zi[2].x += wi2 * x.x; zi[2].y += wi2 * x.y; zi[2].z += wi2 * x.z; zi[2].w += wi2 * x.w;
      zi[3].x += wi3 * x.x; zi[3].y += wi3 * x.y; zi[3].z += wi3 * x.z; zi[3].w += wi3 * x.w;
      zo[0].x += wo0 * x.x; zo[0].y += wo0 * x.y; zo[0].z += wo0 * x.z; zo[0].w += wo0 * x.w;
      zo[1].x += wo1 * x.x; zo[1].y += wo1 * x.y; zo[1].z += wo1 * x.z; zo[1].w += wo1 * x.w;
      zo[2].x += wo2 * x.x; zo[2].y += wo2 * x.y; zo[2].z += wo2 * x.z; zo[2].w += wo2 * x.w;
      zo[3].x += wo3 * x.x; zo[3].y += wo3 * x.y; zo[3].z += wo3 * x.z; zo[3].w += wo3 * x.w;
      mc = m1; wc = w1; ac = a1; bc = b1;
    }
  }

#pragma unroll
  for (int k = 0; k < 4; ++k) {
    zi[k].x += __shfl_xor(zi[k].x, 32);
    zi[k].y += __shfl_xor(zi[k].y, 32);
    zi[k].z += __shfl_xor(zi[k].z, 32);
    zi[k].w += __shfl_xor(zi[k].w, 32);
    zo[k].x += __shfl_xor(zo[k].x, 32);
    zo[k].y += __shfl_xor(zo[k].y, 32);
    zo[k].z += __shfl_xor(zo[k].z, 32);
    zo[k].w += __shfl_xor(zo[k].w, 32);
  }
  if (g == 0) {
#pragma unroll
    for (int k = 0; k < 4; ++k) *(float4*)(&zli[w][k][ch]) = zi[k];
  } else {
#pragma unroll
    for (int k = 0; k < 4; ++k) *(float4*)(&zlo[w][k][ch]) = zo[k];
  }
  __syncthreads();

  const int kk = lane >> 4;
  const int o0 = (lane & 15) * 2;
  const float* Mi = Min + kk * 4096 + o0;
  const float* Mo = Mout + kk * 4096 + o0;
  float acc0 = 0.f, acc1 = 0.f;
  for (int i = 0; i < C; ++i) {
    float a_ = zli[w][kk][i];
    float b_ = zlo[w][kk][i];
    float2 mi = *(const float2*)(Mi + i * 32);
    float2 mo = *(const float2*)(Mo + i * 32);
    acc0 += a_ * mi.x + b_ * mo.x;
    acc1 += a_ * mi.y + b_ * mo.y;
  }
  const float third = 1.f / 3.f;
  h[(size_t)t * C + kk * 32 + o0] = acc0 * third;
  h[(size_t)t * C + kk * 32 + o0 + 1] = acc1 * third;
}

// ---------------- self-loop + bias + BN partial stats -----------------------
__global__ __launch_bounds__(256) void selfloop_kernel(
    float* __restrict__ h, const float* __restrict__ lr,
    const float* __restrict__ lw, const float* __restrict__ bias,
    float* __restrict__ bnsum, float* __restrict__ bnsq) {
  __shared__ float lwl[16384];      // 64 KB: lw[i][j]
  __shared__ float xr[4][8][128];   // 16 KB
  __shared__ float red[256];
  const int tid = threadIdx.x;
  const int w = tid >> 6, lane = tid & 63;
  for (int i = tid; i < 16384; i += 256) lwl[i] = lw[i];
  __syncthreads();

  const int c0 = 2 * lane, c1 = c0 + 1;
  const float lr0 = lr[c0], lr1 = lr[c1];
  const float bv0 = bias[c0], bv1 = bias[c1];
  float s0 = 0.f, s1 = 0.f, sq0 = 0.f, sq1 = 0.f;

  const int wg = blockIdx.x * 4 + w;
  const int nw = gridDim.x * 4;
  for (int rb = wg * 8; rb < V; rb += nw * 8) {
    const int nrows = min(8, V - rb);
    float2 hv[8];
#pragma unroll
    for (int rr = 0; rr < 8; ++rr) {
      if (rr < nrows) {
        hv[rr] = *(const float2*)(h + (size_t)(rb + rr) * C + c0);
      } else {
        hv[rr] = make_float2(0.f, 0.f);
      }
      xr[w][rr][c0] = hv[rr].x * lr0;
      xr[w][rr][c1] = hv[rr].y * lr1;
    }
    float acc[8][2] = {};
    for (int i = 0; i < C; ++i) {
      float2 lwv = *(const float2*)(&lwl[i * C + c0]);
#pragma unroll
      for (int rr = 0; rr < 8; ++rr) {
        float xv = xr[w][rr][i];
        acc[rr][0] += xv * lwv.x;
        acc[rr][1] += xv * lwv.y;
      }
    }
    const float third = 1.f / 3.f;
#pragma unroll
    for (int rr = 0; rr < 8; ++rr) {
      if (rr < nrows) {
        float h0 = hv[rr].x + acc[rr][0] * third + bv0;
        float h1 = hv[rr].y + acc[rr][1] * third + bv1;
        *(float2*)(h + (size_t)(rb + rr) * C + c0) = make_float2(h0, h1);
        s0 += h0; s1 += h1; sq0 += h0 * h0; sq1 += h1 * h1;
      }
    }
  }

  __syncthreads();
  red[tid] = s0; __syncthreads();
  if (tid < 64) {
    float v = red[tid] + red[tid + 64] + red[tid + 128] + red[tid + 192];
    atomicAdd(&bnsum[2 * tid], v);
  }
  __syncthreads();
  red[tid] = s1; __syncthreads();
  if (tid < 64) {
    float v = red[tid] + red[tid + 64] + red[tid + 128] + red[tid + 192];
    atomicAdd(&bnsum[2 * tid + 1], v);
  }
  __syncthreads();
  red[tid] = sq0; __syncthreads();
  if (tid < 64) {
    float v = red[tid] + red[tid + 64] + red[tid + 128] + red[tid + 192];
    atomicAdd(&bnsq[2 * tid], v);
  }
  __syncthreads();
  red[tid] = sq1; __syncthreads();
  if (tid < 64) {
    float v = red[tid] + red[tid + 64] + red[tid + 128] + red[tid + 192];
    atomicAdd(&bnsq[2 * tid + 1], v);
  }
}

// ---------------- BN finalize + tanh (fused) --------------------------------
__global__ void tanh_kernel(float* __restrict__ h,
                            const float* __restrict__ bnsum, const float* __restrict__ bnsq,
                            const float* __restrict__ gamma, const float* __restrict__ beta) {
  int idx = blockIdx.x * 256 + threadIdx.x;
  int base = idx * 4;
  if (base >= V * C) return;
  int j = base & 127;
  const float invV = 1.f / (float)V;
  float4 v = *(float4*)(h + base);
  float o[4] = {v.x, v.y, v.z, v.w};
#pragma unroll
  for (int cidx = 0; cidx < 4; ++cidx) {
    float mean = bnsum[j + cidx] * invV;
    float var = bnsq[j + cidx] * invV - mean * mean;
    float sc = gamma[j + cidx] * rsqrtf(var + 1e-5f);
    float sh = beta[j + cidx] - sc * mean;
    o[cidx] = tanhf(sc * o[cidx] + sh);
  }
  v.x = o[0]; v.y = o[1]; v.z = o[2]; v.w = o[3];
  *(float4*)(h + base) = v;
}

// ---------------- rel_out = rel_repr @ w_rel --------------------------------
__global__ __launch_bounds__(128) void relout_kernel(
    const float* __restrict__ rel, const float* __restrict__ wrel,
    float* __restrict__ out) {
  __shared__ float rr[128];
  int tid = threadIdx.x;
  int row = blockIdx.x;
  rr[tid] = rel[row * C + tid];
  __syncthreads();
  float acc = 0.f;
#pragma unroll 4
  for (int i = 0; i < C; ++i) acc += rr[i] * wrel[i * C + tid];
  out[row * C + tid] = acc;
}

extern "C" void kernel_launch(void* const* d_in, const int* in_sizes, int n_in,
                              void* d_out, int out_size, void* d_ws, size_t ws_size,
                              hipStream_t stream) {
  const float* node_repr  = (const float*)d_in[0];
  const float* rel_repr   = (const float*)d_in[1];
  const int*   src        = (const int*)d_in[2];
  const int*   dst        = (const int*)d_in[3];
  const int*   etype      = (const int*)d_in[4];
  const float* norm       = (const float*)d_in[5];
  const float* node_w     = (const float*)d_in[6];
  const float* node_rel_w = (const float*)d_in[7];
  const float* in_w       = (const float*)d_in[8];
  const float* out_w      = (const float*)d_in[9];
  const float* att_w      = (const float*)d_in[10];
  const float* loop_rel   = (const float*)d_in[11];
  const float* loop_w     = (const float*)d_in[12];
  const float* w_rel      = (const float*)d_in[13];
  const float* bias       = (const float*)d_in[14];
  const float* bn_gamma   = (const float*)d_in[15];
  const float* bn_beta    = (const float*)d_in[16];

  float* out = (float*)d_out;
  float* h = out;                       // [V,128] accumulator, finalized in place
  float* rel_out = out + (size_t)V * C; // [474,128]

  // workspace layout (all float4/h4 users stay 16B-aligned)
  int* cnt = (int*)d_ws;                // V
  int* cur_in = cnt + V;                // V
  int* cin = cur_in + V;                // V (in-edge counts, persists)
  int* cur_out = cin + V;               // V
  float* bnsum = (float*)(cur_out + V); // 128
  float* bnsq = bnsum + 128;            // 128  -- zero region ends (4V+256)
  int* off = (int*)(bnsq + 128);        // V
  int* metas = off + V;                 // E
  float* norms_s = (float*)(metas + E); // E
  int* dsts_s = (int*)(norms_s + E);    // E
  float* wbuf = (float*)(dsts_s + E);   // 4E
  int* bsum = (int*)(wbuf + 4 * (size_t)E); // 256
  float* qbuf = (float*)(bsum + 256);   // 4V
  float* cbuf = qbuf + 4 * V;           // 512
  float* bbuf = cbuf + 512;             // 512
  float* Min = bbuf + 512;              // 16384
  float* Mout = Min + 16384;            // 16384
  _Float16* Mh = (_Float16*)(Mout + 16384); // 32768 halves (f16 B-frag layout)
  _Float16* xs = Mh + 32768;            // E*128 halves (streaming path only)

  const size_t base_bytes = (size_t)((char*)xs - (char*)d_ws);
  const size_t need_bytes = base_bytes + (size_t)E * C * sizeof(_Float16);
  const bool streaming = (ws_size >= need_bytes);

  hipMemsetAsync(cnt, 0, (size_t)(4 * V + 256) * 4, stream);

  prep_kernel<<<(1024 + 32768 + 255) / 256, 256, 0, stream>>>(
      node_rel_w, node_w, in_w, out_w, att_w, cbuf, bbuf, Min, Mout);
  mh_kernel<<<128, 256, 0, stream>>>(Min, Mout, Mh);
  qnode_kernel<<<(V + 15) / 16, 256, 0, stream>>>(node_repr, bbuf, qbuf);
  hist_kernel<<<E / 256, 256, 0, stream>>>(dst, cnt, cin);
  scan_sum_kernel<<<NCHUNK, 256, 0, stream>>>(cnt, bsum);
  scan_top_kernel<<<1, 256, 0, stream>>>(bsum);
  scan_apply_kernel<<<NCHUNK, 256, 0, stream>>>(cnt, bsum, off);
  place_kernel<<<E / 256, 256, 0, stream>>>(dst, src, etype, norm, off, cin,
                                            cur_in, cur_out, metas, norms_s,
                                            dsts_s);
  if (streaming) {
    attw_kernel<true><<<E / 16, 256, 0, stream>>>(node_repr, rel_repr, metas,
                                                  norms_s, dsts_s, qbuf, cbuf,
                                                  wbuf, xs);
    zacc_mfma_kernel<<<(V + 31) / 32, 512, 0, stream>>>(xs, wbuf, cnt, off, cin,
                                                        Mh, h);
  } else {
    attw_kernel<false><<<E / 16, 256, 0, stream>>>(node_repr, rel_repr, metas,
                                                   norms_s, dsts_s, qbuf, cbuf,
                                                   wbuf, nullptr);
    main2_kernel<<<V / 4, 256, 0, stream>>>(node_repr, rel_repr, cnt, off, metas,
                                            wbuf, Min, Mout, h);
  }
  selfloop_kernel<<<1024, 256, 0, stream>>>(h, loop_rel, loop_w, bias, bnsum, bnsq);
  tanh_kernel<<<(V * C / 4 + 255) / 256, 256, 0, stream>>>(h, bnsum, bnsq, bn_gamma, bn_beta);
  relout_kernel<<<NREL2, 128, 0, stream>>>(rel_repr, w_rel, rel_out);
}

// Round 4
// 379.496 us; speedup vs baseline: 1.1489x; 1.0131x over previous
//
#include <hip/hip_runtime.h>

namespace {
constexpr int V = 50000;
constexpr int E = 640000;
constexpr int HALF = 320000;
constexpr int NREL2 = 474;
constexpr int C = 128;
constexpr int NCHUNK = (V + 255) / 256; // 196
}

typedef _Float16 h4 __attribute__((ext_vector_type(4)));
typedef _Float16 h8 __attribute__((ext_vector_type(8)));
typedef _Float16 f16x8 __attribute__((ext_vector_type(8)));
typedef float f32x4 __attribute__((ext_vector_type(4)));

// ---------------- precompute: c[k,i], b[k,i], Min[k,i,o], Mout[k,i,o] -------
__global__ void prep_kernel(const float* __restrict__ nrw, const float* __restrict__ nw,
                            const float* __restrict__ inw, const float* __restrict__ outw,
                            const float* __restrict__ aw,
                            float* __restrict__ cbuf, float* __restrict__ bbuf,
                            float* __restrict__ Min, float* __restrict__ Mout) {
  int tid = blockIdx.x * 256 + threadIdx.x;
  if (tid < 512) {
    int k = tid >> 7, i = tid & 127;
    float acc = 0.f;
    for (int d = 0; d < 32; ++d) acc += nrw[k*4096 + i*32 + d] * aw[d];
    cbuf[tid] = acc;
  } else if (tid < 1024) {
    int u = tid - 512; int k = u >> 7, i = u & 127;
    float acc = 0.f;
    for (int d = 0; d < 32; ++d) acc += nw[k*4096 + i*32 + d] * aw[32 + d];
    bbuf[u] = acc;
  } else if (tid < 1024 + 16384) {
    int u = tid - 1024; int k = u >> 12, rem = u & 4095, i = rem >> 5, o = rem & 31;
    float acc = 0.f;
    for (int d = 0; d < 32; ++d) acc += nrw[k*4096 + i*32 + d] * inw[k*1024 + d*32 + o];
    Min[u] = acc;
  } else if (tid < 1024 + 32768) {
    int u = tid - 1024 - 16384; int k = u >> 12, rem = u & 4095, i = rem >> 5, o = rem & 31;
    float acc = 0.f;
    for (int d = 0; d < 32; ++d) acc += nrw[k*4096 + i*32 + d] * outw[k*1024 + d*32 + o];
    Mout[u] = acc;
  }
}

// ---- Mh: f16 B-fragment layout Mh[dir][k][otile][o16][i128] ----------------
__global__ void mh_kernel(const float* __restrict__ Min, const float* __restrict__ Mout,
                          _Float16* __restrict__ Mh) {
  int u = blockIdx.x * 256 + threadIdx.x;  // 32768 total
  int i = u & 127;
  int o16 = (u >> 7) & 15;
  int ot = (u >> 11) & 1;
  int kk = (u >> 12) & 3;
  int d = (u >> 14) & 1;
  int o = ot * 16 + o16;
  float v = (d ? Mout : Min)[kk * 4096 + i * 32 + o];
  Mh[u] = (_Float16)v;
}

// ---------------- q[t,k] = node_repr[t] . b_k  (16 lanes per node) ----------
__global__ __launch_bounds__(256) void qnode_kernel(const float* __restrict__ nrp,
                                                    const float* __restrict__ bbuf,
                                                    float* __restrict__ qbuf) {
  const int t = blockIdx.x * 16 + (threadIdx.x >> 4);
  const int l = threadIdx.x & 15;
  if (t >= V) return;
  const float* row = nrp + (size_t)t * C + l * 8;
  float4 a0 = *(const float4*)(row);
  float4 a1 = *(const float4*)(row + 4);
  float p[4];
#pragma unroll
  for (int k = 0; k < 4; ++k) {
    const float* brow = bbuf + k * C + l * 8;
    float4 b0 = *(const float4*)(brow);
    float4 b1 = *(const float4*)(brow + 4);
    p[k] = a0.x * b0.x + a0.y * b0.y + a0.z * b0.z + a0.w * b0.w
         + a1.x * b1.x + a1.y * b1.y + a1.z * b1.z + a1.w * b1.w;
  }
#pragma unroll
  for (int m = 1; m < 16; m <<= 1) {
#pragma unroll
    for (int k = 0; k < 4; ++k) p[k] += __shfl_xor(p[k], m);
  }
  if (l == 0) *(float4*)(qbuf + 4 * (size_t)t) = make_float4(p[0], p[1], p[2], p[3]);
}

// ---------------- CSR build (dir-sorted: in-edges first within each node) ---
__global__ void hist_kernel(const int* __restrict__ dst, int* __restrict__ cnt,
                            int* __restrict__ cin) {
  int e = blockIdx.x * 256 + threadIdx.x;
  if (e < E) {
    int t = dst[e];
    atomicAdd(&cnt[t], 1);
    if (e < HALF) atomicAdd(&cin[t], 1);
  }
}

__global__ void scan_sum_kernel(const int* __restrict__ cnt, int* __restrict__ bsum) {
  __shared__ int sd[256];
  int tid = threadIdx.x;
  int idx = blockIdx.x * 256 + tid;
  int v = (idx < V) ? cnt[idx] : 0;
  sd[tid] = v; __syncthreads();
  for (int s = 128; s > 0; s >>= 1) {
    if (tid < s) sd[tid] += sd[tid + s];
    __syncthreads();
  }
  if (tid == 0) bsum[blockIdx.x] = sd[0];
}

__global__ void scan_top_kernel(int* __restrict__ bsum) {
  __shared__ int sd[256];
  int tid = threadIdx.x;
  int v = (tid < NCHUNK) ? bsum[tid] : 0;
  sd[tid] = v; __syncthreads();
  for (int ofs = 1; ofs < 256; ofs <<= 1) {
    int t = (tid >= ofs) ? sd[tid - ofs] : 0;
    __syncthreads();
    sd[tid] += t;
    __syncthreads();
  }
  if (tid < NCHUNK) bsum[tid] = sd[tid] - v;  // exclusive
}

__global__ void scan_apply_kernel(const int* __restrict__ cnt, const int* __restrict__ bsum,
                                  int* __restrict__ off) {
  __shared__ int sd[256];
  int tid = threadIdx.x;
  int idx = blockIdx.x * 256 + tid;
  int v = (idx < V) ? cnt[idx] : 0;
  sd[tid] = v; __syncthreads();
  for (int ofs = 1; ofs < 256; ofs <<= 1) {
    int t = (tid >= ofs) ? sd[tid - ofs] : 0;
    __syncthreads();
    sd[tid] += t;
    __syncthreads();
  }
  if (idx < V) off[idx] = bsum[blockIdx.x] + sd[tid] - v;  // exclusive
}

// place edges: in-edges (e < HALF) packed at off[t], out-edges after cin[t]
__global__ void place_kernel(const int* __restrict__ dst, const int* __restrict__ src,
                             const int* __restrict__ etype, const float* __restrict__ norm,
                             const int* __restrict__ off, const int* __restrict__ cin,
                             int* __restrict__ cur_in, int* __restrict__ cur_out,
                             int* __restrict__ metas, float* __restrict__ norms_s,
                             int* __restrict__ dsts_s) {
  int e = blockIdx.x * 256 + threadIdx.x;
  if (e < E) {
    int t = dst[e];
    int pos;
    if (e < HALF) {
      pos = off[t] + atomicAdd(&cur_in[t], 1);
    } else {
      pos = off[t] + cin[t] + atomicAdd(&cur_out[t], 1);
    }
    metas[pos] = src[e] | (etype[e] << 16) | ((e >= HALF) ? (1 << 25) : 0);
    norms_s[pos] = norm[e];
    dsts_s[pos] = t;
  }
}

// ---------------- phase A: per-edge attention weights (+ optional fp16 x) ---
template <bool WRITE_XS>
__global__ __launch_bounds__(256) void attw_kernel(
    const float* __restrict__ nrp, const float* __restrict__ rel,
    const int* __restrict__ metas, const float* __restrict__ norms_s,
    const int* __restrict__ dsts_s, const float* __restrict__ qbuf,
    const float* __restrict__ cbuf, float* __restrict__ wbuf,
    _Float16* __restrict__ xs) {
  const int i = blockIdx.x * 16 + (threadIdx.x >> 4);  // edge
  const int l = threadIdx.x & 15;                      // 8-channel chunk
  if (i >= E) return;
  const int meta = metas[i];
  const int s = meta & 0xFFFF;
  const int r = (meta >> 16) & 0x1FF;
  const float* arow = nrp + (size_t)s * C + l * 8;
  const float* brow = rel + (size_t)r * C + l * 8;
  float4 a0 = *(const float4*)(arow);
  float4 a1 = *(const float4*)(arow + 4);
  float4 b0 = *(const float4*)(brow);
  float4 b1 = *(const float4*)(brow + 4);
  float x0 = a0.x * b0.x, x1 = a0.y * b0.y, x2 = a0.z * b0.z, x3 = a0.w * b0.w;
  float x4 = a1.x * b1.x, x5 = a1.y * b1.y, x6 = a1.z * b1.z, x7 = a1.w * b1.w;
  if (WRITE_XS) {
    h8 o;
    o[0] = (_Float16)x0; o[1] = (_Float16)x1; o[2] = (_Float16)x2; o[3] = (_Float16)x3;
    o[4] = (_Float16)x4; o[5] = (_Float16)x5; o[6] = (_Float16)x6; o[7] = (_Float16)x7;
    *(h8*)(xs + (size_t)i * C + l * 8) = o;
  }
  float p[4];
#pragma unroll
  for (int k = 0; k < 4; ++k) {
    const float* crow = cbuf + k * C + l * 8;
    float4 c0 = *(const float4*)(crow);
    float4 c1 = *(const float4*)(crow + 4);
    p[k] = x0 * c0.x + x1 * c0.y + x2 * c0.z + x3 * c0.w
         + x4 * c1.x + x5 * c1.y + x6 * c1.z + x7 * c1.w;
  }
#pragma unroll
  for (int m = 1; m < 16; m <<= 1) {
#pragma unroll
    for (int k = 0; k < 4; ++k) p[k] += __shfl_xor(p[k], m);
  }
  const float nr = norms_s[i];
  const int d = dsts_s[i];
  float4 q4 = *(const float4*)(qbuf + 4 * (size_t)d);
  float l0 = fmaxf(p[0] + q4.x, 0.f);
  float l1 = fmaxf(p[1] + q4.y, 0.f);
  float l2 = fmaxf(p[2] + q4.z, 0.f);
  float l3 = fmaxf(p[3] + q4.w, 0.f);
  float mx = fmaxf(fmaxf(l0, l1), fmaxf(l2, l3));
  float e0 = __expf(l0 - mx), e1 = __expf(l1 - mx);
  float e2 = __expf(l2 - mx), e3 = __expf(l3 - mx);
  float inv = nr / (e0 + e1 + e2 + e3);
  if (l == 0) {
    *(float4*)(wbuf + 4 * (size_t)i) =
        make_float4(e0 * inv, e1 * inv, e2 * inv, e3 * inv);
  }
}

// ---------------- phase B (streaming): z accum (f32->f16 LDS) + MFMA --------
__global__ __launch_bounds__(512, 4) void zacc_mfma_kernel(
    const _Float16* __restrict__ xs, const float* __restrict__ wbuf,
    const int* __restrict__ cnt, const int* __restrict__ off,
    const int* __restrict__ nin, const _Float16* __restrict__ Mh,
    float* __restrict__ h) {
  __shared__ __align__(16) _Float16 z16[32768];  // 32 nodes x 2048B, swizzled
  const int w = threadIdx.x >> 6;
  const int lane = threadIdx.x & 63;
  const int g = lane >> 5;   // 0: in-edges, 1: out-edges
  const int l32 = lane & 31;

  // ---- phase 1: accumulate z for this wave's 4 nodes ----
  for (int nn = 0; nn < 4; ++nn) {
    const int node = w * 4 + nn;               // 0..31
    const int t = blockIdx.x * 32 + node;
    int start = 0, deg = 0, ni = 0;
    if (t < V) { start = off[t]; deg = cnt[t]; ni = nin[t]; }
    const int sidx = g ? ni : 0;
    const int nmy = g ? (deg - ni) : ni;
    const int nmax = max(ni, deg - ni);

    float4 z[4];
#pragma unroll
    for (int k = 0; k < 4; ++k) z[k] = make_float4(0.f, 0.f, 0.f, 0.f);

    for (int base = 0; base < nmax; base += 4) {
      h4 xv[4];
      float4 wv[4];
#pragma unroll
      for (int u = 0; u < 4; ++u) {
        int j = base + u;
        int e = start + min(sidx + j, deg - 1);
        xv[u] = ((const h4*)xs)[(size_t)e * 32 + l32];
        float4 t4 = ((const float4*)wbuf)[e];
        bool valid = j < nmy;
        wv[u].x = valid ? t4.x : 0.f;
        wv[u].y = valid ? t4.y : 0.f;
        wv[u].z = valid ? t4.z : 0.f;
        wv[u].w = valid ? t4.w : 0.f;
      }
#pragma unroll
      for (int u = 0; u < 4; ++u) {
        float x0 = (float)xv[u].x, x1 = (float)xv[u].y;
        float x2 = (float)xv[u].z, x3 = (float)xv[u].w;
        z[0].x += wv[u].x * x0; z[0].y += wv[u].x * x1;
        z[0].z += wv[u].x * x2; z[0].w += wv[u].x * x3;
        z[1].x += wv[u].y * x0; z[1].y += wv[u].y * x1;
        z[1].z += wv[u].y * x2; z[1].w += wv[u].y * x3;
        z[2].x += wv[u].z * x0; z[2].y += wv[u].z * x1;
        z[2].z += wv[u].z * x2; z[2].w += wv[u].z * x3;
        z[3].x += wv[u].w * x0; z[3].y += wv[u].w * x1;
        z[3].z += wv[u].w * x2; z[3].w += wv[u].w * x3;
      }
    }

    // write f16 z to swizzled LDS: byte = node*2048 + dir*1024 + k*256
    //                                   + ((l32*8) ^ ((node&7)<<4))
    const int swz = (node & 7) << 4;
    char* zb = (char*)z16 + node * 2048 + g * 1024 + ((l32 * 8) ^ swz);
#pragma unroll
    for (int k = 0; k < 4; ++k) {
      h4 o;
      o.x = (_Float16)z[k].x; o.y = (_Float16)z[k].y;
      o.z = (_Float16)z[k].z; o.w = (_Float16)z[k].w;
      *(h4*)(zb + k * 256) = o;
    }
  }
  __syncthreads();

  // ---- phase 2: MFMA contraction; wave = (k, node-half) ----
  const int kk = w & 3;
  const int nh = w >> 2;
  const int lo16 = lane & 15;       // A row (node) / B col (o) / C col (o)
  const int kq = lane >> 4;         // k-chunk quarter
  {
    const int anode = nh * 16 + lo16;
    const int aswz = (anode & 7) << 4;
    const char* zb = (const char*)z16 + anode * 2048 + kk * 256;
    f16x8 a[2][4];
#pragma unroll
    for (int d = 0; d < 2; ++d)
#pragma unroll
      for (int kc = 0; kc < 4; ++kc)
        a[d][kc] = *(const f16x8*)(zb + d * 1024 + ((kc * 64 + kq * 16) ^ aswz));

    f32x4 c0 = {0.f, 0.f, 0.f, 0.f};
    f32x4 c1 = {0.f, 0.f, 0.f, 0.f};
#pragma unroll
    for (int d = 0; d < 2; ++d)
#pragma unroll
      for (int kc = 0; kc < 4; ++kc) {
        const _Float16* mb = Mh + (((d * 4 + kk) * 2) * 16 + lo16) * 128 + kc * 32 + kq * 8;
        f16x8 b0 = *(const f16x8*)(mb);
        f16x8 b1 = *(const f16x8*)(mb + 2048);
        c0 = __builtin_amdgcn_mfma_f32_16x16x32_f16(a[d][kc], b0, c0, 0, 0, 0);
        c1 = __builtin_amdgcn_mfma_f32_16x16x32_f16(a[d][kc], b1, c1, 0, 0, 0);
      }

    const float third = 1.f / 3.f;
#pragma unroll
    for (int r = 0; r < 4; ++r) {
      int tt = blockIdx.x * 32 + nh * 16 + kq * 4 + r;
      if (tt < V) {
        size_t hb = (size_t)tt * C + kk * 32 + lo16;
        h[hb] = c0[r] * third;
        h[hb + 16] = c1[r] * third;
      }
    }
  }
}

// ---------------- phase B (fallback): gather + accum + contraction ----------
__global__ __launch_bounds__(256) void main2_kernel(
    const float* __restrict__ nrp, const float* __restrict__ rel,
    const int* __restrict__ cnt, const int* __restrict__ off,
    const int* __restrict__ metas, const float* __restrict__ wbuf,
    const float* __restrict__ Min, const float* __restrict__ Mout,
    float* __restrict__ h) {
  __shared__ float zli[4][4][132];
  __shared__ float zlo[4][4][132];
  const int w = threadIdx.x >> 6;
  const int lane = threadIdx.x & 63;
  const int g = lane >> 5;
  const int t = blockIdx.x * 4 + w;
  const int ch = (lane & 31) * 4;

  float4 zi[4], zo[4];
#pragma unroll
  for (int k = 0; k < 4; ++k) {
    zi[k] = make_float4(0.f, 0.f, 0.f, 0.f);
    zo[k] = make_float4(0.f, 0.f, 0.f, 0.f);
  }

  const int start = off[t];
  const int deg = cnt[t];

  for (int base = 0; base < deg; base += 64) {
    const int cn = min(64, deg - base);
    int m_l = 0;
    if (lane < cn) m_l = metas[start + base + lane];
    const int nj = (cn + 1) >> 1;
    int idx0 = min(g, cn - 1);
    bool v0 = (g < cn);
    int mc = __shfl(m_l, idx0);
    float4 wc = *(const float4*)(wbuf + 4 * (size_t)(start + base + idx0));
    if (!v0) { wc.x = 0.f; wc.y = 0.f; wc.z = 0.f; wc.w = 0.f; }
    float4 ac = *(const float4*)(nrp + (size_t)(mc & 0xFFFF) * C + ch);
    float4 bc = *(const float4*)(rel + (size_t)((mc >> 16) & 0x1FF) * C + ch);
    for (int j = 0; j < nj; ++j) {
      int idx1 = 2 * (j + 1) + g;
      bool v1 = (idx1 < cn);
      idx1 = min(idx1, cn - 1);
      int m1 = __shfl(m_l, idx1);
      float4 w1 = *(const float4*)(wbuf + 4 * (size_t)(start + base + idx1));
      if (!v1) { w1.x = 0.f; w1.y = 0.f; w1.z = 0.f; w1.w = 0.f; }
      float4 a1 = *(const float4*)(nrp + (size_t)(m1 & 0xFFFF) * C + ch);
      float4 b1 = *(const float4*)(rel + (size_t)((m1 >> 16) & 0x1FF) * C + ch);

      float4 x;
      x.x = ac.x * bc.x; x.y = ac.y * bc.y; x.z = ac.z * bc.z; x.w = ac.w * bc.w;
      float sif = (mc & (1 << 25)) ? 0.f : 1.f;  // 0 => out-edge
      float wi0 = wc.x * sif, wo0 = wc.x - wi0;
      float wi1 = wc.y * sif, wo1 = wc.y - wi1;
      float wi2 = wc.z * sif, wo2 = wc.z - wi2;
      float wi3 = wc.w * sif, wo3 = wc.w - wi3;
      zi[0].x += wi0 * x.x; zi[0].y += wi0 * x.y; zi[0].z += wi0 * x.z; zi[0].w += wi0 * x.w;
      zi[1].x += wi1 * x.x; zi[1].y += wi1 * x.y; zi[1].z += wi1 * x.z; zi[1].w += wi1 * x.w;
      zi[2].x += wi2 * x.x; zi[2].y += wi2 * x.y; zi[2].z += wi2 * x.z; zi[2].w += wi2 * x.w;
      zi[3].x += wi3 * x.x; zi[3].y += wi3 * x.y; zi[3].z += wi3 * x.z; zi[3].w += wi3 * x.w;
      zo[0].x += wo0 * x.x; zo[0].y += wo0 * x.y; zo[0].z += wo0 * x.z; zo[0].w += wo0 * x.w;
      zo[1].x += wo1 * x.x; zo[1].y += wo1 * x.y; zo[1].z += wo1 * x.z; zo[1].w += wo1 * x.w;
      zo[2].x += wo2 * x.x; zo[2].y += wo2 * x.y; zo[2].z += wo2 * x.z; zo[2].w += wo2 * x.w;
      zo[3].x += wo3 * x.x; zo[3].y += wo3 * x.y; zo[3].z += wo3 * x.z; zo[3].w += wo3 * x.w;
      mc = m1; wc = w1; ac = a1; bc = b1;
    }
  }

#pragma unroll
  for (int k = 0; k < 4; ++k) {
    zi[k].x += __shfl_xor(zi[k].x, 32);
    zi[k].y += __shfl_xor(zi[k].y, 32);
    zi[k].z += __shfl_xor(zi[k].z, 32);
    zi[k].w += __shfl_xor(zi[k].w, 32);
    zo[k].x += __shfl_xor(zo[k].x, 32);
    zo[k].y += __shfl_xor(zo[k].y, 32);
    zo[k].z += __shfl_xor(zo[k].z, 32);
    zo[k].w += __shfl_xor(zo[k].w, 32);
  }
  if (g == 0) {
#pragma unroll
    for (int k = 0; k < 4; ++k) *(float4*)(&zli[w][k][ch]) = zi[k];
  } else {
#pragma unroll
    for (int k = 0; k < 4; ++k) *(float4*)(&zlo[w][k][ch]) = zo[k];
  }
  __syncthreads();

  const int kk = lane >> 4;
  const int o0 = (lane & 15) * 2;
  const float* Mi = Min + kk * 4096 + o0;
  const float* Mo = Mout + kk * 4096 + o0;
  float acc0 = 0.f, acc1 = 0.f;
  for (int i = 0; i < C; ++i) {
    float a_ = zli[w][kk][i];
    float b_ = zlo[w][kk][i];
    float2 mi = *(const float2*)(Mi + i * 32);
    float2 mo = *(const float2*)(Mo + i * 32);
    acc0 += a_ * mi.x + b_ * mo.x;
    acc1 += a_ * mi.y + b_ * mo.y;
  }
  const float third = 1.f / 3.f;
  h[(size_t)t * C + kk * 32 + o0] = acc0 * third;
  h[(size_t)t * C + kk * 32 + o0 + 1] = acc1 * third;
}

// ---------------- self-loop + bias + BN partial stats -----------------------
// lw is read straight from global (64 KB, L1/L2-resident, wave-broadcast) —
// no LDS staging. LDS = 17 KB -> 3-4 blocks/CU instead of 1.
__global__ __launch_bounds__(256, 4) void selfloop_kernel(
    float* __restrict__ h, const float* __restrict__ lr,
    const float* __restrict__ lw, const float* __restrict__ bias,
    float* __restrict__ bnsum, float* __restrict__ bnsq) {
  __shared__ float xr[4][8][128];   // 16 KB
  __shared__ float red[256];
  const int tid = threadIdx.x;
  const int w = tid >> 6, lane = tid & 63;

  const int c0 = 2 * lane, c1 = c0 + 1;
  const float lr0 = lr[c0], lr1 = lr[c1];
  const float bv0 = bias[c0], bv1 = bias[c1];
  float s0 = 0.f, s1 = 0.f, sq0 = 0.f, sq1 = 0.f;

  const int wg = blockIdx.x * 4 + w;
  const int nw = gridDim.x * 4;
  for (int rb = wg * 8; rb < V; rb += nw * 8) {
    const int nrows = min(8, V - rb);
    float2 hv[8];
#pragma unroll
    for (int rr = 0; rr < 8; ++rr) {
      if (rr < nrows) {
        hv[rr] = *(const float2*)(h + (size_t)(rb + rr) * C + c0);
      } else {
        hv[rr] = make_float2(0.f, 0.f);
      }
      xr[w][rr][c0] = hv[rr].x * lr0;
      xr[w][rr][c1] = hv[rr].y * lr1;
    }
    __builtin_amdgcn_s_barrier();  // wave-local xr visibility (whole wave wrote)
    float acc[8][2] = {};
    for (int i = 0; i < C; ++i) {
      float2 lwv = *(const float2*)(lw + i * C + c0);
#pragma unroll
      for (int rr = 0; rr < 8; ++rr) {
        float xv = xr[w][rr][i];
        acc[rr][0] += xv * lwv.x;
        acc[rr][1] += xv * lwv.y;
      }
    }
    const float third = 1.f / 3.f;
#pragma unroll
    for (int rr = 0; rr < 8; ++rr) {
      if (rr < nrows) {
        float h0 = hv[rr].x + acc[rr][0] * third + bv0;
        float h1 = hv[rr].y + acc[rr][1] * third + bv1;
        *(float2*)(h + (size_t)(rb + rr) * C + c0) = make_float2(h0, h1);
        s0 += h0; s1 += h1; sq0 += h0 * h0; sq1 += h1 * h1;
      }
    }
  }

  __syncthreads();
  red[tid] = s0; __syncthreads();
  if (tid < 64) {
    float v = red[tid] + red[tid + 64] + red[tid + 128] + red[tid + 192];
    atomicAdd(&bnsum[2 * tid], v);
  }
  __syncthreads();
  red[tid] = s1; __syncthreads();
  if (tid < 64) {
    float v = red[tid] + red[tid + 64] + red[tid + 128] + red[tid + 192];
    atomicAdd(&bnsum[2 * tid + 1], v);
  }
  __syncthreads();
  red[tid] = sq0; __syncthreads();
  if (tid < 64) {
    float v = red[tid] + red[tid + 64] + red[tid + 128] + red[tid + 192];
    atomicAdd(&bnsq[2 * tid], v);
  }
  __syncthreads();
  red[tid] = sq1; __syncthreads();
  if (tid < 64) {
    float v = red[tid] + red[tid + 64] + red[tid + 128] + red[tid + 192];
    atomicAdd(&bnsq[2 * tid + 1], v);
  }
}

// ---------------- BN finalize + tanh (fused) --------------------------------
__global__ void tanh_kernel(float* __restrict__ h,
                            const float* __restrict__ bnsum, const float* __restrict__ bnsq,
                            const float* __restrict__ gamma, const float* __restrict__ beta) {
  int idx = blockIdx.x * 256 + threadIdx.x;
  int base = idx * 4;
  if (base >= V * C) return;
  int j = base & 127;
  const float invV = 1.f / (float)V;
  float4 v = *(float4*)(h + base);
  float o[4] = {v.x, v.y, v.z, v.w};
#pragma unroll
  for (int cidx = 0; cidx < 4; ++cidx) {
    float mean = bnsum[j + cidx] * invV;
    float var = bnsq[j + cidx] * invV - mean * mean;
    float sc = gamma[j + cidx] * rsqrtf(var + 1e-5f);
    float sh = beta[j + cidx] - sc * mean;
    o[cidx] = tanhf(sc * o[cidx] + sh);
  }
  v.x = o[0]; v.y = o[1]; v.z = o[2]; v.w = o[3];
  *(float4*)(h + base) = v;
}

// ---------------- rel_out = rel_repr @ w_rel --------------------------------
__global__ __launch_bounds__(128) void relout_kernel(
    const float* __restrict__ rel, const float* __restrict__ wrel,
    float* __restrict__ out) {
  __shared__ float rr[128];
  int tid = threadIdx.x;
  int row = blockIdx.x;
  rr[tid] = rel[row * C + tid];
  __syncthreads();
  float acc = 0.f;
#pragma unroll 4
  for (int i = 0; i < C; ++i) acc += rr[i] * wrel[i * C + tid];
  out[row * C + tid] = acc;
}

extern "C" void kernel_launch(void* const* d_in, const int* in_sizes, int n_in,
                              void* d_out, int out_size, void* d_ws, size_t ws_size,
                              hipStream_t stream) {
  const float* node_repr  = (const float*)d_in[0];
  const float* rel_repr   = (const float*)d_in[1];
  const int*   src        = (const int*)d_in[2];
  const int*   dst        = (const int*)d_in[3];
  const int*   etype      = (const int*)d_in[4];
  const float* norm       = (const float*)d_in[5];
  const float* node_w     = (const float*)d_in[6];
  const float* node_rel_w = (const float*)d_in[7];
  const float* in_w       = (const float*)d_in[8];
  const float* out_w      = (const float*)d_in[9];
  const float* att_w      = (const float*)d_in[10];
  const float* loop_rel   = (const float*)d_in[11];
  const float* loop_w     = (const float*)d_in[12];
  const float* w_rel      = (const float*)d_in[13];
  const float* bias       = (const float*)d_in[14];
  const float* bn_gamma   = (const float*)d_in[15];
  const float* bn_beta    = (const float*)d_in[16];

  float* out = (float*)d_out;
  float* h = out;                       // [V,128] accumulator, finalized in place
  float* rel_out = out + (size_t)V * C; // [474,128]

  // workspace layout (all float4/h4 users stay 16B-aligned)
  int* cnt = (int*)d_ws;                // V
  int* cur_in = cnt + V;                // V
  int* cin = cur_in + V;                // V (in-edge counts, persists)
  int* cur_out = cin + V;               // V
  float* bnsum = (float*)(cur_out + V); // 128
  float* bnsq = bnsum + 128;            // 128  -- zero region ends (4V+256)
  int* off = (int*)(bnsq + 128);        // V
  int* metas = off + V;                 // E
  float* norms_s = (float*)(metas + E); // E
  int* dsts_s = (int*)(norms_s + E);    // E
  float* wbuf = (float*)(dsts_s + E);   // 4E
  int* bsum = (int*)(wbuf + 4 * (size_t)E); // 256
  float* qbuf = (float*)(bsum + 256);   // 4V
  float* cbuf = qbuf + 4 * V;           // 512
  float* bbuf = cbuf + 512;             // 512
  float* Min = bbuf + 512;              // 16384
  float* Mout = Min + 16384;            // 16384
  _Float16* Mh = (_Float16*)(Mout + 16384); // 32768 halves (f16 B-frag layout)
  _Float16* xs = Mh + 32768;            // E*128 halves (streaming path only)

  const size_t base_bytes = (size_t)((char*)xs - (char*)d_ws);
  const size_t need_bytes = base_bytes + (size_t)E * C * sizeof(_Float16);
  const bool streaming = (ws_size >= need_bytes);

  hipMemsetAsync(cnt, 0, (size_t)(4 * V + 256) * 4, stream);

  prep_kernel<<<(1024 + 32768 + 255) / 256, 256, 0, stream>>>(
      node_rel_w, node_w, in_w, out_w, att_w, cbuf, bbuf, Min, Mout);
  mh_kernel<<<128, 256, 0, stream>>>(Min, Mout, Mh);
  qnode_kernel<<<(V + 15) / 16, 256, 0, stream>>>(node_repr, bbuf, qbuf);
  hist_kernel<<<E / 256, 256, 0, stream>>>(dst, cnt, cin);
  scan_sum_kernel<<<NCHUNK, 256, 0, stream>>>(cnt, bsum);
  scan_top_kernel<<<1, 256, 0, stream>>>(bsum);
  scan_apply_kernel<<<NCHUNK, 256, 0, stream>>>(cnt, bsum, off);
  place_kernel<<<E / 256, 256, 0, stream>>>(dst, src, etype, norm, off, cin,
                                            cur_in, cur_out, metas, norms_s,
                                            dsts_s);
  if (streaming) {
    attw_kernel<true><<<E / 16, 256, 0, stream>>>(node_repr, rel_repr, metas,
                                                  norms_s, dsts_s, qbuf, cbuf,
                                                  wbuf, xs);
    zacc_mfma_kernel<<<(V + 31) / 32, 512, 0, stream>>>(xs, wbuf, cnt, off, cin,
                                                        Mh, h);
  } else {
    attw_kernel<false><<<E / 16, 256, 0, stream>>>(node_repr, rel_repr, metas,
                                                   norms_s, dsts_s, qbuf, cbuf,
                                                   wbuf, nullptr);
    main2_kernel<<<V / 4, 256, 0, stream>>>(node_repr, rel_repr, cnt, off, metas,
                                            wbuf, Min, Mout, h);
  }
  selfloop_kernel<<<1024, 256, 0, stream>>>(h, loop_rel, loop_w, bias, bnsum, bnsq);
  tanh_kernel<<<(V * C / 4 + 255) / 256, 256, 0, stream>>>(h, bnsum, bnsq, bn_gamma, bn_beta);
  relout_kernel<<<NREL2, 128, 0, stream>>>(rel_repr, w_rel, rel_out);
}

// Round 5
// 372.037 us; speedup vs baseline: 1.1720x; 1.0200x over previous
//
#include <hip/hip_runtime.h>

namespace {
constexpr int V = 50000;
constexpr int E = 640000;
constexpr int HALF = 320000;
constexpr int NREL2 = 474;
constexpr int C = 128;
constexpr int NCHUNK = (V + 255) / 256; // 196
}

typedef _Float16 h4 __attribute__((ext_vector_type(4)));
typedef _Float16 f16x8 __attribute__((ext_vector_type(8)));
typedef float f32x4 __attribute__((ext_vector_type(4)));

// ---------------- precompute: c[k,i], b[k,i], Min[k,i,o], Mout[k,i,o] -------
__global__ void prep_kernel(const float* __restrict__ nrw, const float* __restrict__ nw,
                            const float* __restrict__ inw, const float* __restrict__ outw,
                            const float* __restrict__ aw,
                            float* __restrict__ cbuf, float* __restrict__ bbuf,
                            float* __restrict__ Min, float* __restrict__ Mout) {
  int tid = blockIdx.x * 256 + threadIdx.x;
  if (tid < 512) {
    int k = tid >> 7, i = tid & 127;
    float acc = 0.f;
    for (int d = 0; d < 32; ++d) acc += nrw[k*4096 + i*32 + d] * aw[d];
    cbuf[tid] = acc;
  } else if (tid < 1024) {
    int u = tid - 512; int k = u >> 7, i = u & 127;
    float acc = 0.f;
    for (int d = 0; d < 32; ++d) acc += nw[k*4096 + i*32 + d] * aw[32 + d];
    bbuf[u] = acc;
  } else if (tid < 1024 + 16384) {
    int u = tid - 1024; int k = u >> 12, rem = u & 4095, i = rem >> 5, o = rem & 31;
    float acc = 0.f;
    for (int d = 0; d < 32; ++d) acc += nrw[k*4096 + i*32 + d] * inw[k*1024 + d*32 + o];
    Min[u] = acc;
  } else if (tid < 1024 + 32768) {
    int u = tid - 1024 - 16384; int k = u >> 12, rem = u & 4095, i = rem >> 5, o = rem & 31;
    float acc = 0.f;
    for (int d = 0; d < 32; ++d) acc += nrw[k*4096 + i*32 + d] * outw[k*1024 + d*32 + o];
    Mout[u] = acc;
  }
}

// ---- Mh: f16 B-fragment layout Mh[dir][k][otile][o16][i128] ----------------
__global__ void mh_kernel(const float* __restrict__ Min, const float* __restrict__ Mout,
                          _Float16* __restrict__ Mh) {
  int u = blockIdx.x * 256 + threadIdx.x;  // 32768 total
  int i = u & 127;
  int o16 = (u >> 7) & 15;
  int ot = (u >> 11) & 1;
  int kk = (u >> 12) & 3;
  int d = (u >> 14) & 1;
  int o = ot * 16 + o16;
  float v = (d ? Mout : Min)[kk * 4096 + i * 32 + o];
  Mh[u] = (_Float16)v;
}

// ---------------- q[t,k] = node_repr[t] . b_k  (16 lanes per node) ----------
__global__ __launch_bounds__(256) void qnode_kernel(const float* __restrict__ nrp,
                                                    const float* __restrict__ bbuf,
                                                    float* __restrict__ qbuf) {
  const int t = blockIdx.x * 16 + (threadIdx.x >> 4);
  const int l = threadIdx.x & 15;
  if (t >= V) return;
  const float* row = nrp + (size_t)t * C + l * 8;
  float4 a0 = *(const float4*)(row);
  float4 a1 = *(const float4*)(row + 4);
  float p[4];
#pragma unroll
  for (int k = 0; k < 4; ++k) {
    const float* brow = bbuf + k * C + l * 8;
    float4 b0 = *(const float4*)(brow);
    float4 b1 = *(const float4*)(brow + 4);
    p[k] = a0.x * b0.x + a0.y * b0.y + a0.z * b0.z + a0.w * b0.w
         + a1.x * b1.x + a1.y * b1.y + a1.z * b1.z + a1.w * b1.w;
  }
#pragma unroll
  for (int m = 1; m < 16; m <<= 1) {
#pragma unroll
    for (int k = 0; k < 4; ++k) p[k] += __shfl_xor(p[k], m);
  }
  if (l == 0) *(float4*)(qbuf + 4 * (size_t)t) = make_float4(p[0], p[1], p[2], p[3]);
}

// ---------------- CSR build (dir-sorted: in-edges first within each node) ---
__global__ void hist_kernel(const int* __restrict__ dst, int* __restrict__ cnt,
                            int* __restrict__ cin) {
  int e = blockIdx.x * 256 + threadIdx.x;
  if (e < E) {
    int t = dst[e];
    atomicAdd(&cnt[t], 1);
    if (e < HALF) atomicAdd(&cin[t], 1);
  }
}

__global__ void scan_sum_kernel(const int* __restrict__ cnt, int* __restrict__ bsum) {
  __shared__ int sd[256];
  int tid = threadIdx.x;
  int idx = blockIdx.x * 256 + tid;
  int v = (idx < V) ? cnt[idx] : 0;
  sd[tid] = v; __syncthreads();
  for (int s = 128; s > 0; s >>= 1) {
    if (tid < s) sd[tid] += sd[tid + s];
    __syncthreads();
  }
  if (tid == 0) bsum[blockIdx.x] = sd[0];
}

__global__ void scan_top_kernel(int* __restrict__ bsum) {
  __shared__ int sd[256];
  int tid = threadIdx.x;
  int v = (tid < NCHUNK) ? bsum[tid] : 0;
  sd[tid] = v; __syncthreads();
  for (int ofs = 1; ofs < 256; ofs <<= 1) {
    int t = (tid >= ofs) ? sd[tid - ofs] : 0;
    __syncthreads();
    sd[tid] += t;
    __syncthreads();
  }
  if (tid < NCHUNK) bsum[tid] = sd[tid] - v;  // exclusive
}

__global__ void scan_apply_kernel(const int* __restrict__ cnt, const int* __restrict__ bsum,
                                  int* __restrict__ off) {
  __shared__ int sd[256];
  int tid = threadIdx.x;
  int idx = blockIdx.x * 256 + tid;
  int v = (idx < V) ? cnt[idx] : 0;
  sd[tid] = v; __syncthreads();
  for (int ofs = 1; ofs < 256; ofs <<= 1) {
    int t = (tid >= ofs) ? sd[tid - ofs] : 0;
    __syncthreads();
    sd[tid] += t;
    __syncthreads();
  }
  if (idx < V) off[idx] = bsum[blockIdx.x] + sd[tid] - v;  // exclusive
}

// place edges: in-edges (e < HALF) packed at off[t], out-edges after cin[t]
__global__ void place_kernel(const int* __restrict__ dst, const int* __restrict__ src,
                             const int* __restrict__ etype, const float* __restrict__ norm,
                             const int* __restrict__ off, const int* __restrict__ cin,
                             int* __restrict__ cur_in, int* __restrict__ cur_out,
                             int* __restrict__ metas, float* __restrict__ norms_s) {
  int e = blockIdx.x * 256 + threadIdx.x;
  if (e < E) {
    int t = dst[e];
    int pos;
    if (e < HALF) {
      pos = off[t] + atomicAdd(&cur_in[t], 1);
    } else {
      pos = off[t] + cin[t] + atomicAdd(&cur_out[t], 1);
    }
    metas[pos] = src[e] | (etype[e] << 16);
    norms_s[pos] = norm[e];
  }
}

// ---------------- fused phase A+B: gather + attention + z accum + MFMA ------
// 512 threads, 32 nodes/block. Phase 1: wave w handles nodes w*4..w*4+3;
// lanes 0-31 process in-edges, lanes 32-63 out-edges (CSR dir-sorted).
// Per edge: gather src row (coalesced 512B) + rel row, x = a*b in f32 regs,
// p[k] via register c_k dot + 5-step shfl_xor butterfly, in-lane softmax,
// z[k] += w[k]*x. 2-deep prefetch pipeline hides gather latency. z written
// as f16 to XOR-swizzled LDS. Phase 2: 16x16x32 f16 MFMA contraction vs Mh.
__global__ __launch_bounds__(512, 4) void fused_kernel(
    const float* __restrict__ nrp, const float* __restrict__ rel,
    const int* __restrict__ cnt, const int* __restrict__ off,
    const int* __restrict__ nin, const float* __restrict__ qbuf,
    const float* __restrict__ cbuf, const int* __restrict__ metas,
    const float* __restrict__ norms_s, const _Float16* __restrict__ Mh,
    float* __restrict__ h) {
  __shared__ __align__(16) _Float16 z16[32768];  // 32 nodes x 2048B, swizzled
  const int w = threadIdx.x >> 6;
  const int lane = threadIdx.x & 63;
  const int g = lane >> 5;   // 0: in-edges, 1: out-edges
  const int l32 = lane & 31;
  const int ch = l32 * 4;

  // c_k rows: register-resident for the whole kernel (2 KB, per-lane float4)
  const float4 ck0 = *(const float4*)(cbuf + 0 * C + ch);
  const float4 ck1 = *(const float4*)(cbuf + 1 * C + ch);
  const float4 ck2 = *(const float4*)(cbuf + 2 * C + ch);
  const float4 ck3 = *(const float4*)(cbuf + 3 * C + ch);

  // ---- phase 1: per-node edge loop (both dirs concurrently) ----
  for (int nn = 0; nn < 4; ++nn) {
    const int node = w * 4 + nn;               // 0..31
    const int t = blockIdx.x * 32 + node;
    int start = 0, deg = 0, ni = 0;
    float4 q4 = make_float4(0.f, 0.f, 0.f, 0.f);
    if (t < V) {
      start = off[t]; deg = cnt[t]; ni = nin[t];
      q4 = *(const float4*)(qbuf + 4 * (size_t)t);
    }
    const int sidx = g ? ni : 0;
    const int nmy = g ? (deg - ni) : ni;
    const int nmax = max(ni, deg - ni);

    float4 z0 = make_float4(0.f, 0.f, 0.f, 0.f);
    float4 z1 = make_float4(0.f, 0.f, 0.f, 0.f);
    float4 z2 = make_float4(0.f, 0.f, 0.f, 0.f);
    float4 z3 = make_float4(0.f, 0.f, 0.f, 0.f);

    if (nmax > 0) {
      // prologue: load edge 0 (clamped within this node's segment)
      int e0 = start + min(sidx, deg - 1);
      int meta = metas[e0];
      float nr = norms_s[e0];
      float4 a = *(const float4*)(nrp + (size_t)(meta & 0xFFFF) * C + ch);
      float4 b = *(const float4*)(rel + (size_t)((meta >> 16) & 0x1FF) * C + ch);

      for (int j = 0; j < nmax; ++j) {
        // issue next edge's loads (wave-uniform condition)
        int meta_n = 0; float nr_n = 0.f;
        float4 a_n = a, b_n = b;
        if (j + 1 < nmax) {
          int en = start + min(sidx + j + 1, deg - 1);
          meta_n = metas[en];
          nr_n = norms_s[en];
          a_n = *(const float4*)(nrp + (size_t)(meta_n & 0xFFFF) * C + ch);
          b_n = *(const float4*)(rel + (size_t)((meta_n >> 16) & 0x1FF) * C + ch);
        }
        // compute current edge
        float4 x;
        x.x = a.x * b.x; x.y = a.y * b.y; x.z = a.z * b.z; x.w = a.w * b.w;
        float p0 = x.x * ck0.x + x.y * ck0.y + x.z * ck0.z + x.w * ck0.w;
        float p1 = x.x * ck1.x + x.y * ck1.y + x.z * ck1.z + x.w * ck1.w;
        float p2 = x.x * ck2.x + x.y * ck2.y + x.z * ck2.z + x.w * ck2.w;
        float p3 = x.x * ck3.x + x.y * ck3.y + x.z * ck3.z + x.w * ck3.w;
#pragma unroll
        for (int m = 1; m < 32; m <<= 1) {
          p0 += __shfl_xor(p0, m);
          p1 += __shfl_xor(p1, m);
          p2 += __shfl_xor(p2, m);
          p3 += __shfl_xor(p3, m);
        }
        float l0 = fmaxf(p0 + q4.x, 0.f);
        float l1 = fmaxf(p1 + q4.y, 0.f);
        float l2 = fmaxf(p2 + q4.z, 0.f);
        float l3 = fmaxf(p3 + q4.w, 0.f);
        float mx = fmaxf(fmaxf(l0, l1), fmaxf(l2, l3));
        float e0f = __expf(l0 - mx), e1f = __expf(l1 - mx);
        float e2f = __expf(l2 - mx), e3f = __expf(l3 - mx);
        float inv = nr / (e0f + e1f + e2f + e3f);
        inv = (j < nmy) ? inv : 0.f;
        float w0 = e0f * inv, w1 = e1f * inv, w2 = e2f * inv, w3 = e3f * inv;
        z0.x += w0 * x.x; z0.y += w0 * x.y; z0.z += w0 * x.z; z0.w += w0 * x.w;
        z1.x += w1 * x.x; z1.y += w1 * x.y; z1.z += w1 * x.z; z1.w += w1 * x.w;
        z2.x += w2 * x.x; z2.y += w2 * x.y; z2.z += w2 * x.z; z2.w += w2 * x.w;
        z3.x += w3 * x.x; z3.y += w3 * x.y; z3.z += w3 * x.z; z3.w += w3 * x.w;
        meta = meta_n; nr = nr_n; a = a_n; b = b_n;
      }
    }

    // write f16 z to swizzled LDS: byte = node*2048 + dir*1024 + k*256
    //                                   + ((l32*8) ^ ((node&7)<<4))
    const int swz = (node & 7) << 4;
    char* zb = (char*)z16 + node * 2048 + g * 1024 + ((l32 * 8) ^ swz);
    {
      h4 o;
      o.x = (_Float16)z0.x; o.y = (_Float16)z0.y;
      o.z = (_Float16)z0.z; o.w = (_Float16)z0.w;
      *(h4*)(zb + 0 * 256) = o;
      o.x = (_Float16)z1.x; o.y = (_Float16)z1.y;
      o.z = (_Float16)z1.z; o.w = (_Float16)z1.w;
      *(h4*)(zb + 1 * 256) = o;
      o.x = (_Float16)z2.x; o.y = (_Float16)z2.y;
      o.z = (_Float16)z2.z; o.w = (_Float16)z2.w;
      *(h4*)(zb + 2 * 256) = o;
      o.x = (_Float16)z3.x; o.y = (_Float16)z3.y;
      o.z = (_Float16)z3.z; o.w = (_Float16)z3.w;
      *(h4*)(zb + 3 * 256) = o;
    }
  }
  __syncthreads();

  // ---- phase 2: MFMA contraction; wave = (k, node-half) ----
  const int kk = w & 3;
  const int nh = w >> 2;
  const int lo16 = lane & 15;       // A row (node) / B col (o) / C col (o)
  const int kq = lane >> 4;         // k-chunk quarter
  {
    const int anode = nh * 16 + lo16;
    const int aswz = (anode & 7) << 4;
    const char* zb = (const char*)z16 + anode * 2048 + kk * 256;
    f16x8 a[2][4];
#pragma unroll
    for (int d = 0; d < 2; ++d)
#pragma unroll
      for (int kc = 0; kc < 4; ++kc)
        a[d][kc] = *(const f16x8*)(zb + d * 1024 + ((kc * 64 + kq * 16) ^ aswz));

    f32x4 c0 = {0.f, 0.f, 0.f, 0.f};
    f32x4 c1 = {0.f, 0.f, 0.f, 0.f};
#pragma unroll
    for (int d = 0; d < 2; ++d)
#pragma unroll
      for (int kc = 0; kc < 4; ++kc) {
        const _Float16* mb = Mh + (((d * 4 + kk) * 2) * 16 + lo16) * 128 + kc * 32 + kq * 8;
        f16x8 b0 = *(const f16x8*)(mb);
        f16x8 b1 = *(const f16x8*)(mb + 2048);
        c0 = __builtin_amdgcn_mfma_f32_16x16x32_f16(a[d][kc], b0, c0, 0, 0, 0);
        c1 = __builtin_amdgcn_mfma_f32_16x16x32_f16(a[d][kc], b1, c1, 0, 0, 0);
      }

    const float third = 1.f / 3.f;
#pragma unroll
    for (int r = 0; r < 4; ++r) {
      int tt = blockIdx.x * 32 + nh * 16 + kq * 4 + r;
      if (tt < V) {
        size_t hb = (size_t)tt * C + kk * 32 + lo16;
        h[hb] = c0[r] * third;
        h[hb + 16] = c1[r] * third;
      }
    }
  }
}

// ---------------- self-loop + bias + BN partial stats -----------------------
// lw read straight from global (64 KB, L1/L2-resident, wave-broadcast).
__global__ __launch_bounds__(256, 4) void selfloop_kernel(
    float* __restrict__ h, const float* __restrict__ lr,
    const float* __restrict__ lw, const float* __restrict__ bias,
    float* __restrict__ bnsum, float* __restrict__ bnsq) {
  __shared__ float xr[4][8][128];   // 16 KB
  __shared__ float red[256];
  const int tid = threadIdx.x;
  const int w = tid >> 6, lane = tid & 63;

  const int c0 = 2 * lane, c1 = c0 + 1;
  const float lr0 = lr[c0], lr1 = lr[c1];
  const float bv0 = bias[c0], bv1 = bias[c1];
  float s0 = 0.f, s1 = 0.f, sq0 = 0.f, sq1 = 0.f;

  const int wg = blockIdx.x * 4 + w;
  const int nw = gridDim.x * 4;
  for (int rb = wg * 8; rb < V; rb += nw * 8) {
    const int nrows = min(8, V - rb);
    float2 hv[8];
#pragma unroll
    for (int rr = 0; rr < 8; ++rr) {
      if (rr < nrows) {
        hv[rr] = *(const float2*)(h + (size_t)(rb + rr) * C + c0);
      } else {
        hv[rr] = make_float2(0.f, 0.f);
      }
      xr[w][rr][c0] = hv[rr].x * lr0;
      xr[w][rr][c1] = hv[rr].y * lr1;
    }
    float acc[8][2] = {};
    for (int i = 0; i < C; ++i) {
      float2 lwv = *(const float2*)(lw + i * C + c0);
#pragma unroll
      for (int rr = 0; rr < 8; ++rr) {
        float xv = xr[w][rr][i];
        acc[rr][0] += xv * lwv.x;
        acc[rr][1] += xv * lwv.y;
      }
    }
    const float third = 1.f / 3.f;
#pragma unroll
    for (int rr = 0; rr < 8; ++rr) {
      if (rr < nrows) {
        float h0 = hv[rr].x + acc[rr][0] * third + bv0;
        float h1 = hv[rr].y + acc[rr][1] * third + bv1;
        *(float2*)(h + (size_t)(rb + rr) * C + c0) = make_float2(h0, h1);
        s0 += h0; s1 += h1; sq0 += h0 * h0; sq1 += h1 * h1;
      }
    }
  }

  __syncthreads();
  red[tid] = s0; __syncthreads();
  if (tid < 64) {
    float v = red[tid] + red[tid + 64] + red[tid + 128] + red[tid + 192];
    atomicAdd(&bnsum[2 * tid], v);
  }
  __syncthreads();
  red[tid] = s1; __syncthreads();
  if (tid < 64) {
    float v = red[tid] + red[tid + 64] + red[tid + 128] + red[tid + 192];
    atomicAdd(&bnsum[2 * tid + 1], v);
  }
  __syncthreads();
  red[tid] = sq0; __syncthreads();
  if (tid < 64) {
    float v = red[tid] + red[tid + 64] + red[tid + 128] + red[tid + 192];
    atomicAdd(&bnsq[2 * tid], v);
  }
  __syncthreads();
  red[tid] = sq1; __syncthreads();
  if (tid < 64) {
    float v = red[tid] + red[tid + 64] + red[tid + 128] + red[tid + 192];
    atomicAdd(&bnsq[2 * tid + 1], v);
  }
}

// ---------------- BN finalize + tanh (fused) --------------------------------
__global__ void tanh_kernel(float* __restrict__ h,
                            const float* __restrict__ bnsum, const float* __restrict__ bnsq,
                            const float* __restrict__ gamma, const float* __restrict__ beta) {
  int idx = blockIdx.x * 256 + threadIdx.x;
  int base = idx * 4;
  if (base >= V * C) return;
  int j = base & 127;
  const float invV = 1.f / (float)V;
  float4 v = *(float4*)(h + base);
  float o[4] = {v.x, v.y, v.z, v.w};
#pragma unroll
  for (int cidx = 0; cidx < 4; ++cidx) {
    float mean = bnsum[j + cidx] * invV;
    float var = bnsq[j + cidx] * invV - mean * mean;
    float sc = gamma[j + cidx] * rsqrtf(var + 1e-5f);
    float sh = beta[j + cidx] - sc * mean;
    o[cidx] = tanhf(sc * o[cidx] + sh);
  }
  v.x = o[0]; v.y = o[1]; v.z = o[2]; v.w = o[3];
  *(float4*)(h + base) = v;
}

// ---------------- rel_out = rel_repr @ w_rel --------------------------------
__global__ __launch_bounds__(128) void relout_kernel(
    const float* __restrict__ rel, const float* __restrict__ wrel,
    float* __restrict__ out) {
  __shared__ float rr[128];
  int tid = threadIdx.x;
  int row = blockIdx.x;
  rr[tid] = rel[row * C + tid];
  __syncthreads();
  float acc = 0.f;
#pragma unroll 4
  for (int i = 0; i < C; ++i) acc += rr[i] * wrel[i * C + tid];
  out[row * C + tid] = acc;
}

extern "C" void kernel_launch(void* const* d_in, const int* in_sizes, int n_in,
                              void* d_out, int out_size, void* d_ws, size_t ws_size,
                              hipStream_t stream) {
  const float* node_repr  = (const float*)d_in[0];
  const float* rel_repr   = (const float*)d_in[1];
  const int*   src        = (const int*)d_in[2];
  const int*   dst        = (const int*)d_in[3];
  const int*   etype      = (const int*)d_in[4];
  const float* norm       = (const float*)d_in[5];
  const float* node_w     = (const float*)d_in[6];
  const float* node_rel_w = (const float*)d_in[7];
  const float* in_w       = (const float*)d_in[8];
  const float* out_w      = (const float*)d_in[9];
  const float* att_w      = (const float*)d_in[10];
  const float* loop_rel   = (const float*)d_in[11];
  const float* loop_w     = (const float*)d_in[12];
  const float* w_rel      = (const float*)d_in[13];
  const float* bias       = (const float*)d_in[14];
  const float* bn_gamma   = (const float*)d_in[15];
  const float* bn_beta    = (const float*)d_in[16];

  float* out = (float*)d_out;
  float* h = out;                       // [V,128] accumulator, finalized in place
  float* rel_out = out + (size_t)V * C; // [474,128]

  // workspace layout (all float4 users stay 16B-aligned)
  int* cnt = (int*)d_ws;                // V
  int* cur_in = cnt + V;                // V
  int* cin = cur_in + V;                // V (in-edge counts, persists)
  int* cur_out = cin + V;               // V
  float* bnsum = (float*)(cur_out + V); // 128
  float* bnsq = bnsum + 128;            // 128  -- zero region ends (4V+256)
  int* off = (int*)(bnsq + 128);        // V
  int* metas = off + V;                 // E
  float* norms_s = (float*)(metas + E); // E
  int* bsum = (int*)(norms_s + E);      // 256
  float* qbuf = (float*)(bsum + 256);   // 4V
  float* cbuf = qbuf + 4 * V;           // 512
  float* bbuf = cbuf + 512;             // 512
  float* Min = bbuf + 512;              // 16384
  float* Mout = Min + 16384;            // 16384
  _Float16* Mh = (_Float16*)(Mout + 16384); // 32768 halves (f16 B-frag layout)

  hipMemsetAsync(cnt, 0, (size_t)(4 * V + 256) * 4, stream);

  prep_kernel<<<(1024 + 32768 + 255) / 256, 256, 0, stream>>>(
      node_rel_w, node_w, in_w, out_w, att_w, cbuf, bbuf, Min, Mout);
  mh_kernel<<<128, 256, 0, stream>>>(Min, Mout, Mh);
  qnode_kernel<<<(V + 15) / 16, 256, 0, stream>>>(node_repr, bbuf, qbuf);
  hist_kernel<<<E / 256, 256, 0, stream>>>(dst, cnt, cin);
  scan_sum_kernel<<<NCHUNK, 256, 0, stream>>>(cnt, bsum);
  scan_top_kernel<<<1, 256, 0, stream>>>(bsum);
  scan_apply_kernel<<<NCHUNK, 256, 0, stream>>>(cnt, bsum, off);
  place_kernel<<<E / 256, 256, 0, stream>>>(dst, src, etype, norm, off, cin,
                                            cur_in, cur_out, metas, norms_s);
  fused_kernel<<<(V + 31) / 32, 512, 0, stream>>>(node_repr, rel_repr, cnt, off,
                                                  cin, qbuf, cbuf, metas,
                                                  norms_s, Mh, h);
  selfloop_kernel<<<1024, 256, 0, stream>>>(h, loop_rel, loop_w, bias, bnsum, bnsq);
  tanh_kernel<<<(V * C / 4 + 255) / 256, 256, 0, stream>>>(h, bnsum, bnsq, bn_gamma, bn_beta);
  relout_kernel<<<NREL2, 128, 0, stream>>>(rel_repr, w_rel, rel_out);
}

// Round 6
// 338.742 us; speedup vs baseline: 1.2872x; 1.0983x over previous
//
#include <hip/hip_runtime.h>

namespace {
constexpr int V = 50000;
constexpr int E = 640000;
constexpr int HALF = 320000;
constexpr int NREL2 = 474;
constexpr int C = 128;
constexpr int NCHUNK = (V + 255) / 256; // 196
}

typedef _Float16 h4 __attribute__((ext_vector_type(4)));
typedef _Float16 f16x8 __attribute__((ext_vector_type(8)));
typedef float f32x4 __attribute__((ext_vector_type(4)));

// ---------------- precompute: c[k,i], b[k,i], Min[k,i,o], Mout[k,i,o] -------
__global__ void prep_kernel(const float* __restrict__ nrw, const float* __restrict__ nw,
                            const float* __restrict__ inw, const float* __restrict__ outw,
                            const float* __restrict__ aw,
                            float* __restrict__ cbuf, float* __restrict__ bbuf,
                            float* __restrict__ Min, float* __restrict__ Mout) {
  int tid = blockIdx.x * 256 + threadIdx.x;
  if (tid < 512) {
    int k = tid >> 7, i = tid & 127;
    float acc = 0.f;
    for (int d = 0; d < 32; ++d) acc += nrw[k*4096 + i*32 + d] * aw[d];
    cbuf[tid] = acc;
  } else if (tid < 1024) {
    int u = tid - 512; int k = u >> 7, i = u & 127;
    float acc = 0.f;
    for (int d = 0; d < 32; ++d) acc += nw[k*4096 + i*32 + d] * aw[32 + d];
    bbuf[u] = acc;
  } else if (tid < 1024 + 16384) {
    int u = tid - 1024; int k = u >> 12, rem = u & 4095, i = rem >> 5, o = rem & 31;
    float acc = 0.f;
    for (int d = 0; d < 32; ++d) acc += nrw[k*4096 + i*32 + d] * inw[k*1024 + d*32 + o];
    Min[u] = acc;
  } else if (tid < 1024 + 32768) {
    int u = tid - 1024 - 16384; int k = u >> 12, rem = u & 4095, i = rem >> 5, o = rem & 31;
    float acc = 0.f;
    for (int d = 0; d < 32; ++d) acc += nrw[k*4096 + i*32 + d] * outw[k*1024 + d*32 + o];
    Mout[u] = acc;
  }
}

// ---- Mh: f16 B-fragment layout Mh[dir][k][otile][o16][i128] ----------------
__global__ void mh_kernel(const float* __restrict__ Min, const float* __restrict__ Mout,
                          _Float16* __restrict__ Mh) {
  int u = blockIdx.x * 256 + threadIdx.x;  // 32768 total
  int i = u & 127;
  int o16 = (u >> 7) & 15;
  int ot = (u >> 11) & 1;
  int kk = (u >> 12) & 3;
  int d = (u >> 14) & 1;
  int o = ot * 16 + o16;
  float v = (d ? Mout : Min)[kk * 4096 + i * 32 + o];
  Mh[u] = (_Float16)v;
}

// ---------------- q[t,k] = node_repr[t] . b_k  (16 lanes per node) ----------
__global__ __launch_bounds__(256) void qnode_kernel(const float* __restrict__ nrp,
                                                    const float* __restrict__ bbuf,
                                                    float* __restrict__ qbuf) {
  const int t = blockIdx.x * 16 + (threadIdx.x >> 4);
  const int l = threadIdx.x & 15;
  if (t >= V) return;
  const float* row = nrp + (size_t)t * C + l * 8;
  float4 a0 = *(const float4*)(row);
  float4 a1 = *(const float4*)(row + 4);
  float p[4];
#pragma unroll
  for (int k = 0; k < 4; ++k) {
    const float* brow = bbuf + k * C + l * 8;
    float4 b0 = *(const float4*)(brow);
    float4 b1 = *(const float4*)(brow + 4);
    p[k] = a0.x * b0.x + a0.y * b0.y + a0.z * b0.z + a0.w * b0.w
         + a1.x * b1.x + a1.y * b1.y + a1.z * b1.z + a1.w * b1.w;
  }
#pragma unroll
  for (int m = 1; m < 16; m <<= 1) {
#pragma unroll
    for (int k = 0; k < 4; ++k) p[k] += __shfl_xor(p[k], m);
  }
  if (l == 0) *(float4*)(qbuf + 4 * (size_t)t) = make_float4(p[0], p[1], p[2], p[3]);
}

// ---------------- CSR build (dir-sorted: in-edges first within each node) ---
__global__ void hist_kernel(const int* __restrict__ dst, int* __restrict__ cnt,
                            int* __restrict__ cin) {
  int e = blockIdx.x * 256 + threadIdx.x;
  if (e < E) {
    int t = dst[e];
    atomicAdd(&cnt[t], 1);
    if (e < HALF) atomicAdd(&cin[t], 1);
  }
}

__global__ void scan_sum_kernel(const int* __restrict__ cnt, int* __restrict__ bsum) {
  __shared__ int sd[256];
  int tid = threadIdx.x;
  int idx = blockIdx.x * 256 + tid;
  int v = (idx < V) ? cnt[idx] : 0;
  sd[tid] = v; __syncthreads();
  for (int s = 128; s > 0; s >>= 1) {
    if (tid < s) sd[tid] += sd[tid + s];
    __syncthreads();
  }
  if (tid == 0) bsum[blockIdx.x] = sd[0];
}

__global__ void scan_top_kernel(int* __restrict__ bsum) {
  __shared__ int sd[256];
  int tid = threadIdx.x;
  int v = (tid < NCHUNK) ? bsum[tid] : 0;
  sd[tid] = v; __syncthreads();
  for (int ofs = 1; ofs < 256; ofs <<= 1) {
    int t = (tid >= ofs) ? sd[tid - ofs] : 0;
    __syncthreads();
    sd[tid] += t;
    __syncthreads();
  }
  if (tid < NCHUNK) bsum[tid] = sd[tid] - v;  // exclusive
}

__global__ void scan_apply_kernel(const int* __restrict__ cnt, const int* __restrict__ bsum,
                                  int* __restrict__ off) {
  __shared__ int sd[256];
  int tid = threadIdx.x;
  int idx = blockIdx.x * 256 + tid;
  int v = (idx < V) ? cnt[idx] : 0;
  sd[tid] = v; __syncthreads();
  for (int ofs = 1; ofs < 256; ofs <<= 1) {
    int t = (tid >= ofs) ? sd[tid - ofs] : 0;
    __syncthreads();
    sd[tid] += t;
    __syncthreads();
  }
  if (idx < V) off[idx] = bsum[blockIdx.x] + sd[tid] - v;  // exclusive
}

// place edges: in-edges (e < HALF) packed at off[t], out-edges after cin[t]
__global__ void place_kernel(const int* __restrict__ dst, const int* __restrict__ src,
                             const int* __restrict__ etype, const float* __restrict__ norm,
                             const int* __restrict__ off, const int* __restrict__ cin,
                             int* __restrict__ cur_in, int* __restrict__ cur_out,
                             int* __restrict__ metas, float* __restrict__ norms_s) {
  int e = blockIdx.x * 256 + threadIdx.x;
  if (e < E) {
    int t = dst[e];
    int pos;
    if (e < HALF) {
      pos = off[t] + atomicAdd(&cur_in[t], 1);
    } else {
      pos = off[t] + cin[t] + atomicAdd(&cur_out[t], 1);
    }
    metas[pos] = src[e] | (etype[e] << 16);
    norms_s[pos] = norm[e];
  }
}

// ---------------- fused: gather + attention + z accum + MFMA ----------------
// 256 threads, 16 nodes/block. Phase 1: wave w handles nodes w*4..w*4+3, one
// node at a time. Lane split: dirg=lane>>5 (0:in 1:out), slot=(lane>>4)&1,
// ll=lane&15 -> 16 lanes per edge (8 ch/lane), 4 edges in flight per wave
// iteration (2 per dir). Butterfly = 4 steps over 16 lanes, shared by 4
// edges -> 4 swizzles/edge (was 20). 1-deep a/b prefetch. z written as f16
// to XOR-swizzled LDS (identical byte layout to round-4). Phase 2: wave=k,
// 16x16x32 f16 MFMA contraction vs Mh.
__global__ __launch_bounds__(256) void fused_kernel(
    const float* __restrict__ nrp, const float* __restrict__ rel,
    const int* __restrict__ cnt, const int* __restrict__ off,
    const int* __restrict__ nin, const float* __restrict__ qbuf,
    const float* __restrict__ cbuf, const int* __restrict__ metas,
    const float* __restrict__ norms_s, const _Float16* __restrict__ Mh,
    float* __restrict__ h) {
  __shared__ __align__(16) _Float16 z16[16384];  // 16 nodes x 2048B, swizzled
  const int w = threadIdx.x >> 6;
  const int lane = threadIdx.x & 63;
  const int dirg = lane >> 5;        // 0: in-edges, 1: out-edges
  const int slot = (lane >> 4) & 1;  // edge slot within dir
  const int ll = lane & 15;          // 8-channel chunk
  const int ch0 = ll * 8;

  // c_k chunks: register-resident (8 floats per k)
  float4 ckA[4], ckB[4];
#pragma unroll
  for (int k = 0; k < 4; ++k) {
    ckA[k] = *(const float4*)(cbuf + k * C + ch0);
    ckB[k] = *(const float4*)(cbuf + k * C + ch0 + 4);
  }

  // ---- phase 1: per-node edge loop, 4 edges per wave-iteration ----
  for (int nn = 0; nn < 4; ++nn) {
    const int node = w * 4 + nn;               // 0..15
    const int t = blockIdx.x * 16 + node;
    const int start = off[t];
    const int deg = cnt[t];
    const int ni = nin[t];
    const float4 q4 = *(const float4*)(qbuf + 4 * (size_t)t);
    const int sidx = dirg ? ni : 0;
    const int nmy = dirg ? (deg - ni) : ni;
    const int nmax = max(ni, deg - ni);        // wave-uniform

    float4 zA[4], zB[4];
#pragma unroll
    for (int k = 0; k < 4; ++k) {
      zA[k] = make_float4(0.f, 0.f, 0.f, 0.f);
      zB[k] = make_float4(0.f, 0.f, 0.f, 0.f);
    }

    if (nmax > 0) {
      int e0 = start + min(sidx + slot, deg - 1);
      int meta = metas[e0];
      float nr = norms_s[e0];
      const float* ar = nrp + (size_t)(meta & 0xFFFF) * C + ch0;
      const float* br = rel + (size_t)((meta >> 16) & 0x1FF) * C + ch0;
      float4 a0 = *(const float4*)(ar);
      float4 a1 = *(const float4*)(ar + 4);
      float4 b0 = *(const float4*)(br);
      float4 b1 = *(const float4*)(br + 4);

      for (int j = 0; j < nmax; j += 2) {
        // prefetch next round's edge (wave-uniform condition)
        int meta_n = meta; float nr_n = nr;
        float4 a0n = a0, a1n = a1, b0n = b0, b1n = b1;
        if (j + 2 < nmax) {
          int en = start + min(sidx + j + 2 + slot, deg - 1);
          meta_n = metas[en];
          nr_n = norms_s[en];
          const float* arn = nrp + (size_t)(meta_n & 0xFFFF) * C + ch0;
          const float* brn = rel + (size_t)((meta_n >> 16) & 0x1FF) * C + ch0;
          a0n = *(const float4*)(arn);
          a1n = *(const float4*)(arn + 4);
          b0n = *(const float4*)(brn);
          b1n = *(const float4*)(brn + 4);
        }
        // compute current edge
        float4 xA, xB;
        xA.x = a0.x * b0.x; xA.y = a0.y * b0.y; xA.z = a0.z * b0.z; xA.w = a0.w * b0.w;
        xB.x = a1.x * b1.x; xB.y = a1.y * b1.y; xB.z = a1.z * b1.z; xB.w = a1.w * b1.w;
        float p0 = xA.x * ckA[0].x + xA.y * ckA[0].y + xA.z * ckA[0].z + xA.w * ckA[0].w
                 + xB.x * ckB[0].x + xB.y * ckB[0].y + xB.z * ckB[0].z + xB.w * ckB[0].w;
        float p1 = xA.x * ckA[1].x + xA.y * ckA[1].y + xA.z * ckA[1].z + xA.w * ckA[1].w
                 + xB.x * ckB[1].x + xB.y * ckB[1].y + xB.z * ckB[1].z + xB.w * ckB[1].w;
        float p2 = xA.x * ckA[2].x + xA.y * ckA[2].y + xA.z * ckA[2].z + xA.w * ckA[2].w
                 + xB.x * ckB[2].x + xB.y * ckB[2].y + xB.z * ckB[2].z + xB.w * ckB[2].w;
        float p3 = xA.x * ckA[3].x + xA.y * ckA[3].y + xA.z * ckA[3].z + xA.w * ckA[3].w
                 + xB.x * ckB[3].x + xB.y * ckB[3].y + xB.z * ckB[3].z + xB.w * ckB[3].w;
#pragma unroll
        for (int m = 1; m < 16; m <<= 1) {
          p0 += __shfl_xor(p0, m);
          p1 += __shfl_xor(p1, m);
          p2 += __shfl_xor(p2, m);
          p3 += __shfl_xor(p3, m);
        }
        float l0 = fmaxf(p0 + q4.x, 0.f);
        float l1 = fmaxf(p1 + q4.y, 0.f);
        float l2 = fmaxf(p2 + q4.z, 0.f);
        float l3 = fmaxf(p3 + q4.w, 0.f);
        float mx = fmaxf(fmaxf(l0, l1), fmaxf(l2, l3));
        float e0f = __expf(l0 - mx), e1f = __expf(l1 - mx);
        float e2f = __expf(l2 - mx), e3f = __expf(l3 - mx);
        float inv = nr / (e0f + e1f + e2f + e3f);
        inv = (j + slot < nmy) ? inv : 0.f;
        float w0 = e0f * inv, w1 = e1f * inv, w2 = e2f * inv, w3 = e3f * inv;
        zA[0].x += w0 * xA.x; zA[0].y += w0 * xA.y; zA[0].z += w0 * xA.z; zA[0].w += w0 * xA.w;
        zB[0].x += w0 * xB.x; zB[0].y += w0 * xB.y; zB[0].z += w0 * xB.z; zB[0].w += w0 * xB.w;
        zA[1].x += w1 * xA.x; zA[1].y += w1 * xA.y; zA[1].z += w1 * xA.z; zA[1].w += w1 * xA.w;
        zB[1].x += w1 * xB.x; zB[1].y += w1 * xB.y; zB[1].z += w1 * xB.z; zB[1].w += w1 * xB.w;
        zA[2].x += w2 * xA.x; zA[2].y += w2 * xA.y; zA[2].z += w2 * xA.z; zA[2].w += w2 * xA.w;
        zB[2].x += w2 * xB.x; zB[2].y += w2 * xB.y; zB[2].z += w2 * xB.z; zB[2].w += w2 * xB.w;
        zA[3].x += w3 * xA.x; zA[3].y += w3 * xA.y; zA[3].z += w3 * xA.z; zA[3].w += w3 * xA.w;
        zB[3].x += w3 * xB.x; zB[3].y += w3 * xB.y; zB[3].z += w3 * xB.z; zB[3].w += w3 * xB.w;
        meta = meta_n; nr = nr_n; a0 = a0n; a1 = a1n; b0 = b0n; b1 = b1n;
      }
    }

    // combine the two slots of each dir (lane ^ 16 stays within the dir half)
#pragma unroll
    for (int k = 0; k < 4; ++k) {
      zA[k].x += __shfl_xor(zA[k].x, 16);
      zA[k].y += __shfl_xor(zA[k].y, 16);
      zA[k].z += __shfl_xor(zA[k].z, 16);
      zA[k].w += __shfl_xor(zA[k].w, 16);
      zB[k].x += __shfl_xor(zB[k].x, 16);
      zB[k].y += __shfl_xor(zB[k].y, 16);
      zB[k].z += __shfl_xor(zB[k].z, 16);
      zB[k].w += __shfl_xor(zB[k].w, 16);
    }
    // write f16 z: byte = node*2048 + dir*1024 + k*256 + ((ll*16) ^ swz)
    if (slot == 0) {
      const int swz = (node & 7) << 4;
      char* zb = (char*)z16 + node * 2048 + dirg * 1024 + ((ll * 16) ^ swz);
#pragma unroll
      for (int k = 0; k < 4; ++k) {
        f16x8 o;
        o[0] = (_Float16)zA[k].x; o[1] = (_Float16)zA[k].y;
        o[2] = (_Float16)zA[k].z; o[3] = (_Float16)zA[k].w;
        o[4] = (_Float16)zB[k].x; o[5] = (_Float16)zB[k].y;
        o[6] = (_Float16)zB[k].z; o[7] = (_Float16)zB[k].w;
        *(f16x8*)(zb + k * 256) = o;
      }
    }
  }
  __syncthreads();

  // ---- phase 2: MFMA contraction; wave = k ----
  const int kk = w;
  const int lo16 = lane & 15;       // A row (node) / B col (o) / C col (o)
  const int kq = lane >> 4;         // k-chunk quarter
  {
    const int anode = lo16;
    const int aswz = (anode & 7) << 4;
    const char* zb = (const char*)z16 + anode * 2048 + kk * 256;
    f16x8 a[2][4];
#pragma unroll
    for (int d = 0; d < 2; ++d)
#pragma unroll
      for (int kc = 0; kc < 4; ++kc)
        a[d][kc] = *(const f16x8*)(zb + d * 1024 + ((kc * 64 + kq * 16) ^ aswz));

    f32x4 c0 = {0.f, 0.f, 0.f, 0.f};
    f32x4 c1 = {0.f, 0.f, 0.f, 0.f};
#pragma unroll
    for (int d = 0; d < 2; ++d)
#pragma unroll
      for (int kc = 0; kc < 4; ++kc) {
        const _Float16* mb = Mh + (((d * 4 + kk) * 2) * 16 + lo16) * 128 + kc * 32 + kq * 8;
        f16x8 b0 = *(const f16x8*)(mb);
        f16x8 b1 = *(const f16x8*)(mb + 2048);
        c0 = __builtin_amdgcn_mfma_f32_16x16x32_f16(a[d][kc], b0, c0, 0, 0, 0);
        c1 = __builtin_amdgcn_mfma_f32_16x16x32_f16(a[d][kc], b1, c1, 0, 0, 0);
      }

    const float third = 1.f / 3.f;
#pragma unroll
    for (int r = 0; r < 4; ++r) {
      int tt = blockIdx.x * 16 + kq * 4 + r;
      if (tt < V) {
        size_t hb = (size_t)tt * C + kk * 32 + lo16;
        h[hb] = c0[r] * third;
        h[hb + 16] = c1[r] * third;
      }
    }
  }
}

// ---------------- self-loop + bias + BN partial stats -----------------------
// lw read straight from global (64 KB, L1/L2-resident, wave-broadcast).
__global__ __launch_bounds__(256, 4) void selfloop_kernel(
    float* __restrict__ h, const float* __restrict__ lr,
    const float* __restrict__ lw, const float* __restrict__ bias,
    float* __restrict__ bnsum, float* __restrict__ bnsq) {
  __shared__ float xr[4][8][128];   // 16 KB
  __shared__ float red[256];
  const int tid = threadIdx.x;
  const int w = tid >> 6, lane = tid & 63;

  const int c0 = 2 * lane, c1 = c0 + 1;
  const float lr0 = lr[c0], lr1 = lr[c1];
  const float bv0 = bias[c0], bv1 = bias[c1];
  float s0 = 0.f, s1 = 0.f, sq0 = 0.f, sq1 = 0.f;

  const int wg = blockIdx.x * 4 + w;
  const int nw = gridDim.x * 4;
  for (int rb = wg * 8; rb < V; rb += nw * 8) {
    const int nrows = min(8, V - rb);
    float2 hv[8];
#pragma unroll
    for (int rr = 0; rr < 8; ++rr) {
      if (rr < nrows) {
        hv[rr] = *(const float2*)(h + (size_t)(rb + rr) * C + c0);
      } else {
        hv[rr] = make_float2(0.f, 0.f);
      }
      xr[w][rr][c0] = hv[rr].x * lr0;
      xr[w][rr][c1] = hv[rr].y * lr1;
    }
    float acc[8][2] = {};
    for (int i = 0; i < C; ++i) {
      float2 lwv = *(const float2*)(lw + i * C + c0);
#pragma unroll
      for (int rr = 0; rr < 8; ++rr) {
        float xv = xr[w][rr][i];
        acc[rr][0] += xv * lwv.x;
        acc[rr][1] += xv * lwv.y;
      }
    }
    const float third = 1.f / 3.f;
#pragma unroll
    for (int rr = 0; rr < 8; ++rr) {
      if (rr < nrows) {
        float h0 = hv[rr].x + acc[rr][0] * third + bv0;
        float h1 = hv[rr].y + acc[rr][1] * third + bv1;
        *(float2*)(h + (size_t)(rb + rr) * C + c0) = make_float2(h0, h1);
        s0 += h0; s1 += h1; sq0 += h0 * h0; sq1 += h1 * h1;
      }
    }
  }

  __syncthreads();
  red[tid] = s0; __syncthreads();
  if (tid < 64) {
    float v = red[tid] + red[tid + 64] + red[tid + 128] + red[tid + 192];
    atomicAdd(&bnsum[2 * tid], v);
  }
  __syncthreads();
  red[tid] = s1; __syncthreads();
  if (tid < 64) {
    float v = red[tid] + red[tid + 64] + red[tid + 128] + red[tid + 192];
    atomicAdd(&bnsum[2 * tid + 1], v);
  }
  __syncthreads();
  red[tid] = sq0; __syncthreads();
  if (tid < 64) {
    float v = red[tid] + red[tid + 64] + red[tid + 128] + red[tid + 192];
    atomicAdd(&bnsq[2 * tid], v);
  }
  __syncthreads();
  red[tid] = sq1; __syncthreads();
  if (tid < 64) {
    float v = red[tid] + red[tid + 64] + red[tid + 128] + red[tid + 192];
    atomicAdd(&bnsq[2 * tid + 1], v);
  }
}

// ---------------- BN finalize + tanh (fused) --------------------------------
__global__ void tanh_kernel(float* __restrict__ h,
                            const float* __restrict__ bnsum, const float* __restrict__ bnsq,
                            const float* __restrict__ gamma, const float* __restrict__ beta) {
  int idx = blockIdx.x * 256 + threadIdx.x;
  int base = idx * 4;
  if (base >= V * C) return;
  int j = base & 127;
  const float invV = 1.f / (float)V;
  float4 v = *(float4*)(h + base);
  float o[4] = {v.x, v.y, v.z, v.w};
#pragma unroll
  for (int cidx = 0; cidx < 4; ++cidx) {
    float mean = bnsum[j + cidx] * invV;
    float var = bnsq[j + cidx] * invV - mean * mean;
    float sc = gamma[j + cidx] * rsqrtf(var + 1e-5f);
    float sh = beta[j + cidx] - sc * mean;
    o[cidx] = tanhf(sc * o[cidx] + sh);
  }
  v.x = o[0]; v.y = o[1]; v.z = o[2]; v.w = o[3];
  *(float4*)(h + base) = v;
}

// ---------------- rel_out = rel_repr @ w_rel --------------------------------
__global__ __launch_bounds__(128) void relout_kernel(
    const float* __restrict__ rel, const float* __restrict__ wrel,
    float* __restrict__ out) {
  __shared__ float rr[128];
  int tid = threadIdx.x;
  int row = blockIdx.x;
  rr[tid] = rel[row * C + tid];
  __syncthreads();
  float acc = 0.f;
#pragma unroll 4
  for (int i = 0; i < C; ++i) acc += rr[i] * wrel[i * C + tid];
  out[row * C + tid] = acc;
}

extern "C" void kernel_launch(void* const* d_in, const int* in_sizes, int n_in,
                              void* d_out, int out_size, void* d_ws, size_t ws_size,
                              hipStream_t stream) {
  const float* node_repr  = (const float*)d_in[0];
  const float* rel_repr   = (const float*)d_in[1];
  const int*   src        = (const int*)d_in[2];
  const int*   dst        = (const int*)d_in[3];
  const int*   etype      = (const int*)d_in[4];
  const float* norm       = (const float*)d_in[5];
  const float* node_w     = (const float*)d_in[6];
  const float* node_rel_w = (const float*)d_in[7];
  const float* in_w       = (const float*)d_in[8];
  const float* out_w      = (const float*)d_in[9];
  const float* att_w      = (const float*)d_in[10];
  const float* loop_rel   = (const float*)d_in[11];
  const float* loop_w     = (const float*)d_in[12];
  const float* w_rel      = (const float*)d_in[13];
  const float* bias       = (const float*)d_in[14];
  const float* bn_gamma   = (const float*)d_in[15];
  const float* bn_beta    = (const float*)d_in[16];

  float* out = (float*)d_out;
  float* h = out;                       // [V,128] accumulator, finalized in place
  float* rel_out = out + (size_t)V * C; // [474,128]

  // workspace layout (all float4 users stay 16B-aligned)
  int* cnt = (int*)d_ws;                // V
  int* cur_in = cnt + V;                // V
  int* cin = cur_in + V;                // V (in-edge counts, persists)
  int* cur_out = cin + V;               // V
  float* bnsum = (float*)(cur_out + V); // 128
  float* bnsq = bnsum + 128;            // 128  -- zero region ends (4V+256)
  int* off = (int*)(bnsq + 128);        // V
  int* metas = off + V;                 // E
  float* norms_s = (float*)(metas + E); // E
  int* bsum = (int*)(norms_s + E);      // 256
  float* qbuf = (float*)(bsum + 256);   // 4V
  float* cbuf = qbuf + 4 * V;           // 512
  float* bbuf = cbuf + 512;             // 512
  float* Min = bbuf + 512;              // 16384
  float* Mout = Min + 16384;            // 16384
  _Float16* Mh = (_Float16*)(Mout + 16384); // 32768 halves (f16 B-frag layout)

  hipMemsetAsync(cnt, 0, (size_t)(4 * V + 256) * 4, stream);

  prep_kernel<<<(1024 + 32768 + 255) / 256, 256, 0, stream>>>(
      node_rel_w, node_w, in_w, out_w, att_w, cbuf, bbuf, Min, Mout);
  mh_kernel<<<128, 256, 0, stream>>>(Min, Mout, Mh);
  qnode_kernel<<<(V + 15) / 16, 256, 0, stream>>>(node_repr, bbuf, qbuf);
  hist_kernel<<<E / 256, 256, 0, stream>>>(dst, cnt, cin);
  scan_sum_kernel<<<NCHUNK, 256, 0, stream>>>(cnt, bsum);
  scan_top_kernel<<<1, 256, 0, stream>>>(bsum);
  scan_apply_kernel<<<NCHUNK, 256, 0, stream>>>(cnt, bsum, off);
  place_kernel<<<E / 256, 256, 0, stream>>>(dst, src, etype, norm, off, cin,
                                            cur_in, cur_out, metas, norms_s);
  fused_kernel<<<(V + 15) / 16, 256, 0, stream>>>(node_repr, rel_repr, cnt, off,
                                                  cin, qbuf, cbuf, metas,
                                                  norms_s, Mh, h);
  selfloop_kernel<<<1024, 256, 0, stream>>>(h, loop_rel, loop_w, bias, bnsum, bnsq);
  tanh_kernel<<<(V * C / 4 + 255) / 256, 256, 0, stream>>>(h, bnsum, bnsq, bn_gamma, bn_beta);
  relout_kernel<<<NREL2, 128, 0, stream>>>(rel_repr, w_rel, rel_out);
}